// Round 12
// baseline (496.277 us; speedup 1.0000x reference)
//
#include <hip/hip_runtime.h>
#include <hip/hip_bf16.h>

#define N_NODES 100000
#define N_EDGES 1600000
#define BATCH   16384
#define HID     128

#define SHIFT 9
#define BSZ   512
#define NB    196
#define EPB   8192

#define FS 264   // LDS A-tile row stride (shorts); 528 B, 16B-aligned rows
#define RS 136   // relay row stride (shorts)

typedef __attribute__((ext_vector_type(8))) short bf16x8;
typedef __attribute__((ext_vector_type(4))) float fx4;
typedef __attribute__((ext_vector_type(2))) float fx2;

__device__ inline short f2bf(float f) {
    unsigned u = __builtin_bit_cast(unsigned, f);
    unsigned r = (u + 0x7FFF + ((u >> 16) & 1)) >> 16;
    return (short)r;
}
__device__ inline float bf2f(short s) {
    unsigned u = ((unsigned)(unsigned short)s) << 16;
    return __builtin_bit_cast(float, u);
}

// ---------------- CSR build: bucketed two-pass ----------------

__global__ __launch_bounds__(256) void k_bhist(const int* __restrict__ dst,
                                               int* __restrict__ bcnt, int E) {
    __shared__ int lh[NB];
    int t = threadIdx.x;
    for (int j = t; j < NB; j += 256) lh[j] = 0;
    __syncthreads();
    int base = blockIdx.x * 4096;
    int n = min(4096, E - base);
    for (int i = t; i < n; i += 256) atomicAdd(&lh[dst[base + i] >> SHIFT], 1);
    __syncthreads();
    for (int j = t; j < NB; j += 256)
        if (lh[j]) atomicAdd(&bcnt[j], lh[j]);
}

__global__ void k_bscan(const int* __restrict__ bcnt, int* __restrict__ bbase,
                        int* __restrict__ bcur, int* __restrict__ offsets) {
    __shared__ int sh[256];
    int t = threadIdx.x;
    int c = (t < NB) ? bcnt[t] : 0;
    sh[t] = c;
    __syncthreads();
    for (int off = 1; off < 256; off <<= 1) {
        int v = 0;
        if (t >= off) v = sh[t - off];
        __syncthreads();
        if (t >= off) sh[t] += v;
        __syncthreads();
    }
    int incl = sh[t];
    int excl = incl - c;
    if (t < NB) { bbase[t] = excl; bcur[t] = excl; }
    if (t == NB - 1) { bbase[NB] = incl; offsets[N_NODES] = incl; }
}

__global__ __launch_bounds__(256) void k_passA(
    const int* __restrict__ edge, int* __restrict__ bcur,
    unsigned* __restrict__ tmp, int E) {
    __shared__ unsigned staged[EPB];
    __shared__ unsigned char bkt[EPB];
    __shared__ int lh[NB], lstart[NB], gbase[NB], lcur[NB];
    int t = threadIdx.x;
    int base = blockIdx.x * EPB;
    int n = min(EPB, E - base);
    for (int j = t; j < NB; j += 256) lh[j] = 0;
    __syncthreads();
    for (int i = t; i < n; i += 256)
        atomicAdd(&lh[edge[E + base + i] >> SHIFT], 1);
    __syncthreads();
    if (t == 0) {
        int run = 0;
        for (int b = 0; b < NB; ++b) { lstart[b] = run; run += lh[b]; }
    }
    __syncthreads();
    if (t < NB) {
        gbase[t] = atomicAdd(&bcur[t], lh[t]);
        lcur[t] = lstart[t];
    }
    __syncthreads();
    for (int i = t; i < n; i += 256) {
        int s = edge[base + i];
        int d = edge[E + base + i];
        int b = d >> SHIFT;
        unsigned p = (unsigned)s | ((unsigned)(d & (BSZ - 1)) << 17);
        int pos = atomicAdd(&lcur[b], 1);
        staged[pos] = p;
        bkt[pos] = (unsigned char)b;
    }
    __syncthreads();
    for (int i = t; i < n; i += 256) {
        int b = bkt[i];
        tmp[gbase[b] + (i - lstart[b])] = staged[i];
    }
}

__global__ __launch_bounds__(256) void k_passB(
    const unsigned* __restrict__ tmp, const int* __restrict__ bbase,
    int* __restrict__ offsets, float* __restrict__ dinv,
    float* __restrict__ rdeg, int* __restrict__ col) {
    __shared__ int lh[BSZ];
    __shared__ int lsum[256];
    int b = blockIdx.x, t = threadIdx.x;
    int begin = bbase[b], end = bbase[b + 1];
    lh[t] = 0; lh[t + 256] = 0;
    __syncthreads();
    for (int i = begin + t; i < end; i += 256)
        atomicAdd(&lh[tmp[i] >> 17], 1);
    __syncthreads();
    int c0 = lh[2 * t], c1 = lh[2 * t + 1];
    int tsum = c0 + c1;
    lsum[t] = tsum;
    __syncthreads();
    for (int off = 1; off < 256; off <<= 1) {
        int v = 0;
        if (t >= off) v = lsum[t - off];
        __syncthreads();
        if (t >= off) lsum[t] += v;
        __syncthreads();
    }
    int texcl = lsum[t] - tsum;
    int node0 = (b << SHIFT) + 2 * t;
    if (node0 < N_NODES) {
        offsets[node0] = begin + texcl;
        dinv[node0] = rsqrtf((float)c0 + 1.f);
        rdeg[node0] = sqrtf((float)c0 + 1.f);
    }
    if (node0 + 1 < N_NODES) {
        offsets[node0 + 1] = begin + texcl + c0;
        dinv[node0 + 1] = rsqrtf((float)c1 + 1.f);
        rdeg[node0 + 1] = sqrtf((float)c1 + 1.f);
    }
    __syncthreads();
    lh[2 * t] = texcl;
    lh[2 * t + 1] = texcl + c0;
    __syncthreads();
    for (int i = begin + t; i < end; i += 1024) {
        int i1 = i + 256, i2 = i + 512, i3 = i + 768;
        unsigned p0 = tmp[i];
        unsigned p1 = (i1 < end) ? tmp[i1] : 0u;
        unsigned p2 = (i2 < end) ? tmp[i2] : 0u;
        unsigned p3 = (i3 < end) ? tmp[i3] : 0u;
        int pos0 = begin + atomicAdd(&lh[p0 >> 17], 1);
        col[pos0] = (int)(p0 & 0x1FFFFu);
        if (i1 < end) { int q = begin + atomicAdd(&lh[p1 >> 17], 1); col[q] = (int)(p1 & 0x1FFFFu); }
        if (i2 < end) { int q = begin + atomicAdd(&lh[p2 >> 17], 1); col[q] = (int)(p2 & 0x1FFFFu); }
        if (i3 < end) { int q = begin + atomicAdd(&lh[p3 >> 17], 1); col[q] = (int)(p3 & 0x1FFFFu); }
    }
}

// ---------------- weight prep: fp32 W[k][n] -> interleaved hi/lo, transposed ----------------

__global__ void k_prepW(const float* __restrict__ Wc0, const float* __restrict__ Wc1,
                        const float* __restrict__ Wc2, const float* __restrict__ Wp,
                        const float* __restrict__ Ww, short* __restrict__ wI) {
    int c = blockIdx.x;
    const float* src;
    int koff = 0;
    if (c == 0) src = Wc0;
    else if (c == 1) src = Wc1;
    else if (c == 2) src = Wc2;
    else if (c < 6) { src = Wp; koff = (c - 3) * 128; }
    else { src = Ww; koff = (c - 6) * 128; }
    short* d = wI + (size_t)c * 32768;
    for (int i = threadIdx.x; i < 16384; i += 256) {
        int k = i >> 7, n = i & 127;
        float v = src[(size_t)(koff + k) * 128 + n];
        short h = f2bf(v);
        short l = f2bf(v - bf2f(h));
        int c16 = k >> 3, j = k & 7;
        d[n * 256 + c16 * 16 + j] = h;
        d[n * 256 + c16 * 16 + 8 + j] = l;
    }
}

// ---------------- z0 prep: z0[v] = bf16(dinv[v] * x[v]) ----------------

__global__ __launch_bounds__(256) void k_prepZ0(const float* __restrict__ x,
                                                const float* __restrict__ dinv,
                                                short* __restrict__ z0) {
    int i = blockIdx.x * 256 + threadIdx.x;      // unit = 8 floats
    if (i >= N_NODES * 16) return;
    int v = i >> 4;
    float dv = dinv[v];
    const float* p = x + (size_t)i * 8;
    float4 va = *(const float4*)p;
    float4 vb = *(const float4*)(p + 4);
    float vv[8] = {va.x, va.y, va.z, va.w, vb.x, vb.y, vb.z, vb.w};
    bf16x8 o;
#pragma unroll
    for (int j = 0; j < 8; ++j) o[j] = f2bf(vv[j] * dv);
    *(bf16x8*)&z0[(size_t)i * 8] = o;
}

// ---------------- fused aggregate + GEMM ----------------
// y[v] = sum_{s in N(v)} zin[s] + zin[v]   (zin pre-scaled by dinv)
// x_out = relu((y*dinv[v]) @ W + bias); outputs split hi/lo, optionally
// re-scaled by oscale (=dinv) for the next layer's gather.
// Block: 128 threads (2 waves), 32 nodes. sidx!=null -> compact batch mode.

__device__ inline void addrow(uint4 u, fx2* a) {
    a[0] += (fx2){__builtin_bit_cast(float, u.x << 16),
                  __builtin_bit_cast(float, u.x & 0xFFFF0000u)};
    a[1] += (fx2){__builtin_bit_cast(float, u.y << 16),
                  __builtin_bit_cast(float, u.y & 0xFFFF0000u)};
    a[2] += (fx2){__builtin_bit_cast(float, u.z << 16),
                  __builtin_bit_cast(float, u.z & 0xFFFF0000u)};
    a[3] += (fx2){__builtin_bit_cast(float, u.w << 16),
                  __builtin_bit_cast(float, u.w & 0xFFFF0000u)};
}

__global__ __launch_bounds__(128) void k_fused(
    const short* __restrict__ zin, const int* __restrict__ col,
    const int* __restrict__ offs, const float* __restrict__ dinv,
    const float* __restrict__ bias, const short* __restrict__ WI,
    short* __restrict__ outh, short* __restrict__ outl,
    const float* __restrict__ oscale,
    const int* __restrict__ sidx, const int* __restrict__ tidx) {
    __shared__ __align__(16) short ldsA[32 * FS];   // 16.9 KB; reused as relay
    int t = threadIdx.x;
    int w = t >> 6, lane = t & 63;
    int g = lane >> 4, li = lane & 15;
    int blockBase = blockIdx.x << 5;

    // ---- phase 1: each wave aggregates its 16 nodes ----
    for (int i = 0; i < 16; ++i) {
        int r = (w << 4) + i;
        int idx = blockBase + r;
        int v = idx;
        if (sidx) v = (idx < BATCH) ? sidx[idx] : tidx[idx - BATCH];
        int beg = offs[v], end = offs[v + 1];
        float dv = dinv[v];
        fx2 a4[4] = {{0.f,0.f},{0.f,0.f},{0.f,0.f},{0.f,0.f}};
        if (g == 0)
            addrow(*(const uint4*)&zin[(size_t)v * 128 + (li << 3)], a4);
        int e = beg + g;
        for (; e + 12 < end; e += 16) {
            int s0 = col[e], s1 = col[e + 4], s2 = col[e + 8], s3 = col[e + 12];
            uint4 u0 = *(const uint4*)&zin[(size_t)s0 * 128 + (li << 3)];
            uint4 u1 = *(const uint4*)&zin[(size_t)s1 * 128 + (li << 3)];
            uint4 u2 = *(const uint4*)&zin[(size_t)s2 * 128 + (li << 3)];
            uint4 u3 = *(const uint4*)&zin[(size_t)s3 * 128 + (li << 3)];
            addrow(u0, a4); addrow(u1, a4); addrow(u2, a4); addrow(u3, a4);
        }
        for (; e < end; e += 4)
            addrow(*(const uint4*)&zin[(size_t)col[e] * 128 + (li << 3)], a4);

        float a[8];
#pragma unroll
        for (int j = 0; j < 4; ++j) { a[2 * j] = a4[j][0]; a[2 * j + 1] = a4[j][1]; }
#pragma unroll
        for (int off = 16; off <= 32; off <<= 1)
#pragma unroll
            for (int j = 0; j < 8; ++j) a[j] += __shfl_xor(a[j], off);
        if (g == 0) {
            bf16x8 hh, ll;
#pragma unroll
            for (int j = 0; j < 8; ++j) {
                float zv = a[j] * dv;                 // A = y * dinv[v]
                short hb = f2bf(zv);
                hh[j] = hb;
                ll[j] = f2bf(zv - bf2f(hb));
            }
            *(bf16x8*)&ldsA[r * FS + (li << 4)] = hh;
            *(bf16x8*)&ldsA[r * FS + (li << 4) + 8] = ll;
        }
    }
    // same-wave LDS RAW: in-order per-wave LDS; phase 2 reads own wave's rows only.

    // ---- phase 2: wave w GEMMs rows w*16..w*16+15 over all 128 cols ----
    fx4 acc[8];
#pragma unroll
    for (int j = 0; j < 8; ++j) {
        acc[j][0] = 0.f; acc[j][1] = 0.f; acc[j][2] = 0.f; acc[j][3] = 0.f;
    }
#pragma unroll
    for (int ks = 0; ks < 4; ++ks) {
        int chunk = (ks << 2) + g;
        const short* ap = &ldsA[((w << 4) + li) * FS + (chunk << 4)];
        bf16x8 ah = *(const bf16x8*)ap;
        bf16x8 al = *(const bf16x8*)(ap + 8);
#pragma unroll
        for (int fc = 0; fc < 8; ++fc) {
            int c = (fc << 4) + li;
            const short* bp = &WI[((size_t)c << 8) + (chunk << 4)];
            bf16x8 bh = *(const bf16x8*)bp;
            bf16x8 bl = *(const bf16x8*)(bp + 8);
            acc[fc] = __builtin_amdgcn_mfma_f32_16x16x32_bf16(ah, bh, acc[fc], 0, 0, 0);
            acc[fc] = __builtin_amdgcn_mfma_f32_16x16x32_bf16(ah, bl, acc[fc], 0, 0, 0);
            acc[fc] = __builtin_amdgcn_mfma_f32_16x16x32_bf16(al, bh, acc[fc], 0, 0, 0);
        }
    }

    int rl0 = (w << 4) + (g << 2);
    float dvo[4];
#pragma unroll
    for (int rg = 0; rg < 4; ++rg)
        dvo[rg] = oscale ? oscale[blockBase + rl0 + rg] : 1.f;

    __syncthreads();      // all waves done reading ldsA before relay overwrite
    short* relay = ldsA;

    // hi pass
#pragma unroll
    for (int fc = 0; fc < 8; ++fc) {
        int cl = (fc << 4) + li;
        float bv = bias[cl];
#pragma unroll
        for (int rg = 0; rg < 4; ++rg) {
            float val = fmaxf(acc[fc][rg] + bv, 0.f) * dvo[rg];
            relay[(rl0 + rg) * RS + cl] = f2bf(val);
        }
    }
    __syncthreads();
    {
        int row = t >> 2, seg = t & 3;       // 32 shorts per thread
        const short* sp = &relay[row * RS + (seg << 5)];
        short* dp = &outh[((size_t)(blockBase + row) << 7) + (seg << 5)];
        ((uint4*)dp)[0] = ((const uint4*)sp)[0];
        ((uint4*)dp)[1] = ((const uint4*)sp)[1];
        ((uint4*)dp)[2] = ((const uint4*)sp)[2];
        ((uint4*)dp)[3] = ((const uint4*)sp)[3];
    }
    __syncthreads();
    // lo pass
#pragma unroll
    for (int fc = 0; fc < 8; ++fc) {
        int cl = (fc << 4) + li;
        float bv = bias[cl];
#pragma unroll
        for (int rg = 0; rg < 4; ++rg) {
            float val = fmaxf(acc[fc][rg] + bv, 0.f) * dvo[rg];
            relay[(rl0 + rg) * RS + cl] = f2bf(val - bf2f(f2bf(val)));
        }
    }
    __syncthreads();
    {
        int row = t >> 2, seg = t & 3;
        const short* sp = &relay[row * RS + (seg << 5)];
        short* dp = &outl[((size_t)(blockBase + row) << 7) + (seg << 5)];
        ((uint4*)dp)[0] = ((const uint4*)sp)[0];
        ((uint4*)dp)[1] = ((const uint4*)sp)[1];
        ((uint4*)dp)[2] = ((const uint4*)sp)[2];
        ((uint4*)dp)[3] = ((const uint4*)sp)[3];
    }
}

// ---------------- fused P/Q projection + dot ----------------
// chunks 0,1: z1,z2 (scaled hi/lo; acc rescaled by rdeg after); chunk 2: x3 compact.

__global__ __launch_bounds__(256) void k_pq(
    const short* __restrict__ z1h, const short* __restrict__ z1l,
    const short* __restrict__ z2h, const short* __restrict__ z2l,
    const short* __restrict__ x3h, const short* __restrict__ x3l,
    const float* __restrict__ rdeg, const short* __restrict__ wI,
    const int* __restrict__ sidx, const int* __restrict__ tidx,
    const float* __restrict__ bp, const float* __restrict__ bw,
    float* __restrict__ out) {
    __shared__ float Ps[32][132];
    __shared__ float Qs[32][132];
    int t = threadIdx.x;
    int lane = t & 63, wave = t >> 6;
    int isQ = wave >> 1, wn = wave & 1;
    int l15 = lane & 15;
    int g = lane >> 4;
    int g3 = g << 3;          // A k-offset in plain 128-short rows
    int g16 = g << 4;         // B chunk offset in interleaved 256-short cols
    int pairBase = blockIdx.x << 5;
    int colBase = wn << 6;
    const int* gidx = isQ ? tidx : sidx;
    const float* bias = isQ ? bw : bp;
    int r0i = pairBase + l15;
    int r1i = r0i + 16;
    long long n0 = (long long)gidx[r0i];
    long long n1 = (long long)gidx[r1i];

    fx4 acc[2][4];
#pragma unroll
    for (int i = 0; i < 2; ++i)
#pragma unroll
        for (int j = 0; j < 4; ++j) {
            acc[i][j][0] = 0.f; acc[i][j][1] = 0.f;
            acc[i][j][2] = 0.f; acc[i][j][3] = 0.f;
        }

#pragma unroll
    for (int c = 0; c < 2; ++c) {
        const short* Ah = c ? z2h : z1h;
        const short* Al = c ? z2l : z1l;
        const short* WB = wI + (size_t)(3 + isQ * 3 + c) * 32768;
#pragma unroll
        for (int ks = 0; ks < 4; ++ks) {
            int ko = (ks << 5) + g3;
            bf16x8 a0h = *(const bf16x8*)&Ah[n0 * 128 + ko];
            bf16x8 a0l = *(const bf16x8*)&Al[n0 * 128 + ko];
            bf16x8 a1h = *(const bf16x8*)&Ah[n1 * 128 + ko];
            bf16x8 a1l = *(const bf16x8*)&Al[n1 * 128 + ko];
            int co = (ks << 6) + g16;
#pragma unroll
            for (int fc = 0; fc < 4; ++fc) {
                int cc = colBase + (fc << 4) + l15;
                const short* bpp = &WB[((size_t)cc << 8) + co];
                bf16x8 bh = *(const bf16x8*)bpp;
                bf16x8 bl = *(const bf16x8*)(bpp + 8);
                acc[0][fc] = __builtin_amdgcn_mfma_f32_16x16x32_bf16(a0h, bh, acc[0][fc], 0, 0, 0);
                acc[0][fc] = __builtin_amdgcn_mfma_f32_16x16x32_bf16(a0h, bl, acc[0][fc], 0, 0, 0);
                acc[0][fc] = __builtin_amdgcn_mfma_f32_16x16x32_bf16(a0l, bh, acc[0][fc], 0, 0, 0);
                acc[1][fc] = __builtin_amdgcn_mfma_f32_16x16x32_bf16(a1h, bh, acc[1][fc], 0, 0, 0);
                acc[1][fc] = __builtin_amdgcn_mfma_f32_16x16x32_bf16(a1h, bl, acc[1][fc], 0, 0, 0);
                acc[1][fc] = __builtin_amdgcn_mfma_f32_16x16x32_bf16(a1l, bh, acc[1][fc], 0, 0, 0);
            }
        }
    }

    // rescale by rdeg (undo the dinv pre-scale of z rows), per output row
    int rqv = g << 2;
#pragma unroll
    for (int fr = 0; fr < 2; ++fr)
#pragma unroll
        for (int rg = 0; rg < 4; ++rg) {
            float rd = rdeg[gidx[pairBase + (fr << 4) + rqv + rg]];
#pragma unroll
            for (int fc = 0; fc < 4; ++fc)
                acc[fr][fc][rg] *= rd;
        }

    // chunk 2: x3 compact (unscaled)
    {
        long long b0 = (long long)(r0i + (isQ << 14));
        long long b1 = (long long)(r1i + (isQ << 14));
        const short* WB = wI + (size_t)(3 + isQ * 3 + 2) * 32768;
#pragma unroll
        for (int ks = 0; ks < 4; ++ks) {
            int ko = (ks << 5) + g3;
            bf16x8 a0h = *(const bf16x8*)&x3h[b0 * 128 + ko];
            bf16x8 a0l = *(const bf16x8*)&x3l[b0 * 128 + ko];
            bf16x8 a1h = *(const bf16x8*)&x3h[b1 * 128 + ko];
            bf16x8 a1l = *(const bf16x8*)&x3l[b1 * 128 + ko];
            int co = (ks << 6) + g16;
#pragma unroll
            for (int fc = 0; fc < 4; ++fc) {
                int cc = colBase + (fc << 4) + l15;
                const short* bpp = &WB[((size_t)cc << 8) + co];
                bf16x8 bh = *(const bf16x8*)bpp;
                bf16x8 bl = *(const bf16x8*)(bpp + 8);
                acc[0][fc] = __builtin_amdgcn_mfma_f32_16x16x32_bf16(a0h, bh, acc[0][fc], 0, 0, 0);
                acc[0][fc] = __builtin_amdgcn_mfma_f32_16x16x32_bf16(a0h, bl, acc[0][fc], 0, 0, 0);
                acc[0][fc] = __builtin_amdgcn_mfma_f32_16x16x32_bf16(a0l, bh, acc[0][fc], 0, 0, 0);
                acc[1][fc] = __builtin_amdgcn_mfma_f32_16x16x32_bf16(a1h, bh, acc[1][fc], 0, 0, 0);
                acc[1][fc] = __builtin_amdgcn_mfma_f32_16x16x32_bf16(a1h, bl, acc[1][fc], 0, 0, 0);
                acc[1][fc] = __builtin_amdgcn_mfma_f32_16x16x32_bf16(a1l, bh, acc[1][fc], 0, 0, 0);
            }
        }
    }

    int rq = g << 2;
    float (*dst)[132] = isQ ? Qs : Ps;
#pragma unroll
    for (int fr = 0; fr < 2; ++fr) {
#pragma unroll
        for (int fc = 0; fc < 4; ++fc) {
            int cg = colBase + (fc << 4) + l15;
            float bv = bias[cg];
#pragma unroll
            for (int rg = 0; rg < 4; ++rg)
                dst[(fr << 4) + rq + rg][cg] = acc[fr][fc][rg] + bv;
        }
    }
    __syncthreads();

    int p = t >> 3, seg = t & 7;
    const float* pr = &Ps[p][seg * 16];
    const float* qr = &Qs[p][seg * 16];
    float s = 0.f;
#pragma unroll
    for (int j = 0; j < 16; ++j) s += pr[j] * qr[j];
    s += __shfl_xor(s, 1);
    s += __shfl_xor(s, 2);
    s += __shfl_xor(s, 4);
    if (seg == 0) out[pairBase + p] = s;
}

// ---------------- launch ----------------

extern "C" void kernel_launch(void* const* d_in, const int* in_sizes, int n_in,
                              void* d_out, int out_size, void* d_ws, size_t ws_size,
                              hipStream_t stream) {
    const float* x    = (const float*)d_in[0];
    const int*   edge = (const int*)d_in[1];
    const int*   sidx = (const int*)d_in[2];
    const int*   tidx = (const int*)d_in[3];
    const float* Wc0  = (const float*)d_in[4];
    const float* bc0  = (const float*)d_in[5];
    const float* Wc1  = (const float*)d_in[6];
    const float* bc1  = (const float*)d_in[7];
    const float* Wc2  = (const float*)d_in[8];
    const float* bc2  = (const float*)d_in[9];
    const float* Ww   = (const float*)d_in[10];
    const float* bw   = (const float*)d_in[11];
    const float* Wp   = (const float*)d_in[12];
    const float* bp   = (const float*)d_in[13];
    float* out = (float*)d_out;

    char* base = (char*)d_ws;
    size_t off = 0;
    auto alloc = [&](size_t bytes) -> char* {
        char* p = base + off;
        off = (off + bytes + 255) & ~(size_t)255;
        return p;
    };
    const size_t ZSZ = (size_t)N_NODES * HID * sizeof(short);      // 25.6 MB
    const size_t XSZ = (size_t)2 * BATCH * HID * sizeof(short);    // 8.4 MB
    short* z0   = (short*)alloc(ZSZ);
    short* z1h  = (short*)alloc(ZSZ);
    short* z1l  = (short*)alloc(ZSZ);
    short* z2h  = (short*)alloc(ZSZ);
    short* z2l  = (short*)alloc(ZSZ);
    short* x3h  = (short*)alloc(XSZ);
    short* x3l  = (short*)alloc(XSZ);
    int*   offsets = (int*)alloc((size_t)(N_NODES + 1) * sizeof(int));
    int*   colArr  = (int*)alloc((size_t)N_EDGES * sizeof(int));
    unsigned* tmp  = (unsigned*)alloc((size_t)N_EDGES * sizeof(unsigned));
    float* dinv    = (float*)alloc((size_t)N_NODES * sizeof(float));
    float* rdeg    = (float*)alloc((size_t)N_NODES * sizeof(float));
    int*   bcnt    = (int*)alloc(256 * sizeof(int));
    int*   bbase   = (int*)alloc(256 * sizeof(int));
    int*   bcur    = (int*)alloc(256 * sizeof(int));
    short* wI      = (short*)alloc((size_t)9 * 32768 * sizeof(short));
    (void)ws_size; (void)in_sizes; (void)n_in; (void)out_size;

    // ---- CSR build ----
    hipMemsetAsync(bcnt, 0, NB * sizeof(int), stream);
    k_bhist<<<(N_EDGES + 4095) / 4096, 256, 0, stream>>>(edge + N_EDGES, bcnt, N_EDGES);
    k_bscan<<<1, 256, 0, stream>>>(bcnt, bbase, bcur, offsets);
    k_passA<<<(N_EDGES + EPB - 1) / EPB, 256, 0, stream>>>(edge, bcur, tmp, N_EDGES);
    k_passB<<<NB, 256, 0, stream>>>(tmp, bbase, offsets, dinv, rdeg, colArr);

    // ---- prep ----
    k_prepW<<<9, 256, 0, stream>>>(Wc0, Wc1, Wc2, Wp, Ww, wI);
    k_prepZ0<<<(N_NODES * 16 + 255) / 256, 256, 0, stream>>>(x, dinv, z0);

#define WI(c) (wI + (size_t)(c) * 32768)
    const int fullGrid = N_NODES / 32;        // 3125 (exact)
    const int cmpGrid  = (2 * BATCH) / 32;    // 1024 (exact)

    // ---- layer 1 ----
    k_fused<<<fullGrid, 128, 0, stream>>>(z0, colArr, offsets, dinv, bc0, WI(0),
                                          z1h, z1l, dinv, nullptr, nullptr);
    // ---- layer 2 ----
    k_fused<<<fullGrid, 128, 0, stream>>>(z1h, colArr, offsets, dinv, bc1, WI(1),
                                          z2h, z2l, dinv, nullptr, nullptr);
    // ---- layer 3 (batch nodes only, compact, unscaled) ----
    k_fused<<<cmpGrid, 128, 0, stream>>>(z2h, colArr, offsets, dinv, bc2, WI(2),
                                         x3h, x3l, nullptr, sidx, tidx);

    // ---- fused P/Q + dot ----
    k_pq<<<BATCH / 32, 256, 0, stream>>>(z1h, z1l, z2h, z2l, x3h, x3l, rdeg,
                                         wI, sidx, tidx, bp, bw, out);
}

// Round 13
// 368.839 us; speedup vs baseline: 1.3455x; 1.3455x over previous
//
#include <hip/hip_runtime.h>
#include <hip/hip_bf16.h>

#define N_NODES 100000
#define N_EDGES 1600000
#define BATCH   16384
#define HID     128

#define SHIFT 9
#define BSZ   512
#define NB    196
#define EPB   8192

typedef __attribute__((ext_vector_type(8))) short bf16x8;
typedef __attribute__((ext_vector_type(4))) float fx4;
typedef __attribute__((ext_vector_type(2))) float fx2;

__device__ inline short f2bf(float f) {
    unsigned u = __builtin_bit_cast(unsigned, f);
    unsigned r = (u + 0x7FFF + ((u >> 16) & 1)) >> 16;
    return (short)r;
}
__device__ inline float bf2f(short s) {
    unsigned u = ((unsigned)(unsigned short)s) << 16;
    return __builtin_bit_cast(float, u);
}

// ---------------- CSR build: bucketed two-pass ----------------

__global__ __launch_bounds__(256) void k_bhist(const int* __restrict__ dst,
                                               int* __restrict__ bcnt, int E) {
    __shared__ int lh[NB];
    int t = threadIdx.x;
    for (int j = t; j < NB; j += 256) lh[j] = 0;
    __syncthreads();
    int base = blockIdx.x * 4096;
    int n = min(4096, E - base);
    for (int i = t; i < n; i += 256) atomicAdd(&lh[dst[base + i] >> SHIFT], 1);
    __syncthreads();
    for (int j = t; j < NB; j += 256)
        if (lh[j]) atomicAdd(&bcnt[j], lh[j]);
}

__global__ void k_bscan(const int* __restrict__ bcnt, int* __restrict__ bbase,
                        int* __restrict__ bcur, int* __restrict__ offsets) {
    __shared__ int sh[256];
    int t = threadIdx.x;
    int c = (t < NB) ? bcnt[t] : 0;
    sh[t] = c;
    __syncthreads();
    for (int off = 1; off < 256; off <<= 1) {
        int v = 0;
        if (t >= off) v = sh[t - off];
        __syncthreads();
        if (t >= off) sh[t] += v;
        __syncthreads();
    }
    int incl = sh[t];
    int excl = incl - c;
    if (t < NB) { bbase[t] = excl; bcur[t] = excl; }
    if (t == NB - 1) { bbase[NB] = incl; offsets[N_NODES] = incl; }
}

__global__ __launch_bounds__(256) void k_passA(
    const int* __restrict__ edge, int* __restrict__ bcur,
    unsigned* __restrict__ tmp, int E) {
    __shared__ unsigned staged[EPB];
    __shared__ unsigned char bkt[EPB];
    __shared__ int lh[NB], lstart[NB], gbase[NB], lcur[NB];
    int t = threadIdx.x;
    int base = blockIdx.x * EPB;
    int n = min(EPB, E - base);
    for (int j = t; j < NB; j += 256) lh[j] = 0;
    __syncthreads();
    for (int i = t; i < n; i += 256)
        atomicAdd(&lh[edge[E + base + i] >> SHIFT], 1);
    __syncthreads();
    if (t == 0) {
        int run = 0;
        for (int b = 0; b < NB; ++b) { lstart[b] = run; run += lh[b]; }
    }
    __syncthreads();
    if (t < NB) {
        gbase[t] = atomicAdd(&bcur[t], lh[t]);
        lcur[t] = lstart[t];
    }
    __syncthreads();
    for (int i = t; i < n; i += 256) {
        int s = edge[base + i];
        int d = edge[E + base + i];
        int b = d >> SHIFT;
        unsigned p = (unsigned)s | ((unsigned)(d & (BSZ - 1)) << 17);
        int pos = atomicAdd(&lcur[b], 1);
        staged[pos] = p;
        bkt[pos] = (unsigned char)b;
    }
    __syncthreads();
    for (int i = t; i < n; i += 256) {
        int b = bkt[i];
        tmp[gbase[b] + (i - lstart[b])] = staged[i];
    }
}

__global__ __launch_bounds__(256) void k_passB(
    const unsigned* __restrict__ tmp, const int* __restrict__ bbase,
    int* __restrict__ offsets, float* __restrict__ dinv,
    int* __restrict__ col) {
    __shared__ int lh[BSZ];
    __shared__ int lsum[256];
    int b = blockIdx.x, t = threadIdx.x;
    int begin = bbase[b], end = bbase[b + 1];
    lh[t] = 0; lh[t + 256] = 0;
    __syncthreads();
    for (int i = begin + t; i < end; i += 256)
        atomicAdd(&lh[tmp[i] >> 17], 1);
    __syncthreads();
    int c0 = lh[2 * t], c1 = lh[2 * t + 1];
    int tsum = c0 + c1;
    lsum[t] = tsum;
    __syncthreads();
    for (int off = 1; off < 256; off <<= 1) {
        int v = 0;
        if (t >= off) v = lsum[t - off];
        __syncthreads();
        if (t >= off) lsum[t] += v;
        __syncthreads();
    }
    int texcl = lsum[t] - tsum;
    int node0 = (b << SHIFT) + 2 * t;
    if (node0 < N_NODES) {
        offsets[node0] = begin + texcl;
        dinv[node0] = rsqrtf((float)c0 + 1.f);
    }
    if (node0 + 1 < N_NODES) {
        offsets[node0 + 1] = begin + texcl + c0;
        dinv[node0 + 1] = rsqrtf((float)c1 + 1.f);
    }
    __syncthreads();
    lh[2 * t] = texcl;
    lh[2 * t + 1] = texcl + c0;
    __syncthreads();
    for (int i = begin + t; i < end; i += 1024) {
        int i1 = i + 256, i2 = i + 512, i3 = i + 768;
        unsigned p0 = tmp[i];
        unsigned p1 = (i1 < end) ? tmp[i1] : 0u;
        unsigned p2 = (i2 < end) ? tmp[i2] : 0u;
        unsigned p3 = (i3 < end) ? tmp[i3] : 0u;
        int pos0 = begin + atomicAdd(&lh[p0 >> 17], 1);
        col[pos0] = (int)(p0 & 0x1FFFFu);
        if (i1 < end) { int q = begin + atomicAdd(&lh[p1 >> 17], 1); col[q] = (int)(p1 & 0x1FFFFu); }
        if (i2 < end) { int q = begin + atomicAdd(&lh[p2 >> 17], 1); col[q] = (int)(p2 & 0x1FFFFu); }
        if (i3 < end) { int q = begin + atomicAdd(&lh[p3 >> 17], 1); col[q] = (int)(p3 & 0x1FFFFu); }
    }
}

// ---------------- weight prep: fp32 W[k][n] -> interleaved hi/lo, transposed ----------------

__global__ void k_prepW(const float* __restrict__ Wc0, const float* __restrict__ Wc1,
                        const float* __restrict__ Wc2, const float* __restrict__ Wp,
                        const float* __restrict__ Ww, short* __restrict__ wI) {
    int c = blockIdx.x;
    const float* src;
    int koff = 0;
    if (c == 0) src = Wc0;
    else if (c == 1) src = Wc1;
    else if (c == 2) src = Wc2;
    else if (c < 6) { src = Wp; koff = (c - 3) * 128; }
    else { src = Ww; koff = (c - 6) * 128; }
    short* d = wI + (size_t)c * 32768;
    for (int i = threadIdx.x; i < 16384; i += 256) {
        int k = i >> 7, n = i & 127;
        float v = src[(size_t)(koff + k) * 128 + n];
        short h = f2bf(v);
        short l = f2bf(v - bf2f(h));
        int c16 = k >> 3, j = k & 7;
        d[n * 256 + c16 * 16 + j] = h;
        d[n * 256 + c16 * 16 + 8 + j] = l;
    }
}

// ---------------- pipelined persistent-block GEMM, 32-row tiles ----------------
// A row = 512 bytes (fp32 x OR interleaved bf16 hi/lo). Tile = 32 rows = 16 KB.
// Double-buffered global_load_lds staging, XOR-swizzled (source + read sides).
// 4 waves; wave = 32 rows x 32 cols; B (32 cols, interleaved) in registers.

__device__ inline void stage_tile(char* __restrict__ buf, const char* __restrict__ A,
                                  int tile, int maxRow, int t) {
    int rowBase = tile << 5;
#pragma unroll
    for (int j = 0; j < 4; ++j) {
        int s = (j << 8) + t;            // 16B slot 0..1023
        int row = s >> 5;
        int cpos = s & 31;
        int c = cpos ^ (row & 7);        // pre-swizzled source chunk
        int gr = rowBase + row;
        if (gr > maxRow) gr = maxRow;
        const char* src = A + ((size_t)gr << 9) + (c << 4);
        char* dst = buf + (((j << 8) + (t & 192)) << 4);   // wave-uniform base
        __builtin_amdgcn_global_load_lds(
            (const __attribute__((address_space(1))) unsigned*)src,
            (__attribute__((address_space(3))) unsigned*)dst, 16, 0, 0);
    }
}

template<int ISF32>
__global__ __launch_bounds__(256) void k_sgemm(
    const char* __restrict__ A, const short* __restrict__ WI,
    short* __restrict__ outb, const float* __restrict__ scale, int M) {
    __shared__ __align__(16) char lds[32768];
    int t = threadIdx.x;
    int lane = t & 63, wave = t >> 6;
    int l15 = lane & 15, g = lane >> 4;
    int colBase = wave << 5;
    int rq = g << 2;

    // ---- B into registers (once): this wave's 32 cols ----
    bf16x8 Bh[4][2], Bl[4][2];
#pragma unroll
    for (int ks = 0; ks < 4; ++ks)
#pragma unroll
        for (int fc = 0; fc < 2; ++fc) {
            int c = colBase + (fc << 4) + l15;
            const short* bp = &WI[((size_t)c << 8) + (((ks << 2) + g) << 4)];
            Bh[ks][fc] = *(const bf16x8*)bp;
            Bl[ks][fc] = *(const bf16x8*)(bp + 8);
        }

    int nT = (M + 31) >> 5;
    int maxRow = M - 1;
    int tile = blockIdx.x;
    if (tile < nT) stage_tile(lds, A, tile, maxRow, t);
    int cur = 0;

    for (; tile < nT; tile += gridDim.x) {
        __syncthreads();                       // drains vmcnt -> buf[cur] ready
        int nxt = tile + gridDim.x;
        if (nxt < nT) stage_tile(lds + ((cur ^ 1) << 14), A, nxt, maxRow, t);
        char* buf = lds + (cur << 14);

        fx4 acc[2][2];
#pragma unroll
        for (int i = 0; i < 2; ++i)
#pragma unroll
            for (int j = 0; j < 2; ++j) {
                acc[i][j][0] = 0.f; acc[i][j][1] = 0.f;
                acc[i][j][2] = 0.f; acc[i][j][3] = 0.f;
            }

#pragma unroll
        for (int ks = 0; ks < 4; ++ks) {
            bf16x8 ah[2], al[2];
#pragma unroll
            for (int fr = 0; fr < 2; ++fr) {
                int row = (fr << 4) + l15;
                int c0 = (ks << 3) + (g << 1);
                const char* p0 = buf + (row << 9) + ((c0 ^ (row & 7)) << 4);
                const char* p1 = buf + (row << 9) + (((c0 + 1) ^ (row & 7)) << 4);
                if (ISF32) {
                    float v[8];
                    *(float4*)&v[0] = *(const float4*)p0;
                    *(float4*)&v[4] = *(const float4*)p1;
#pragma unroll
                    for (int j = 0; j < 8; ++j) {
                        short hb = f2bf(v[j]);
                        ah[fr][j] = hb;
                        al[fr][j] = f2bf(v[j] - bf2f(hb));
                    }
                } else {
                    ah[fr] = *(const bf16x8*)p0;
                    al[fr] = *(const bf16x8*)p1;
                }
            }
#pragma unroll
            for (int fc = 0; fc < 2; ++fc) {
                acc[0][fc] = __builtin_amdgcn_mfma_f32_16x16x32_bf16(ah[0], Bh[ks][fc], acc[0][fc], 0, 0, 0);
                acc[0][fc] = __builtin_amdgcn_mfma_f32_16x16x32_bf16(ah[0], Bl[ks][fc], acc[0][fc], 0, 0, 0);
                acc[0][fc] = __builtin_amdgcn_mfma_f32_16x16x32_bf16(al[0], Bh[ks][fc], acc[0][fc], 0, 0, 0);
                acc[1][fc] = __builtin_amdgcn_mfma_f32_16x16x32_bf16(ah[1], Bh[ks][fc], acc[1][fc], 0, 0, 0);
                acc[1][fc] = __builtin_amdgcn_mfma_f32_16x16x32_bf16(ah[1], Bl[ks][fc], acc[1][fc], 0, 0, 0);
                acc[1][fc] = __builtin_amdgcn_mfma_f32_16x16x32_bf16(al[1], Bh[ks][fc], acc[1][fc], 0, 0, 0);
            }
        }

        // all waves done reading buf[cur]; prefetch (vmcnt) stays in flight
        __builtin_amdgcn_s_barrier();

        // ---- epilogue via freed buf[cur]: fragment -> row-contiguous stores ----
        // relay: per-wave [32 rows][40 shorts] (80B stride, 16B-aligned)
        short* relay = (short*)buf + wave * 1280;
        int rowBaseG = tile << 5;
#pragma unroll
        for (int fr = 0; fr < 2; ++fr)
#pragma unroll
            for (int rg = 0; rg < 4; ++rg) {
                int rl = (fr << 4) + rq + rg;
                int R = rowBaseG + rl;
                float sc = (R < M) ? scale[R] : 0.f;
#pragma unroll
                for (int fc = 0; fc < 2; ++fc)
                    relay[rl * 40 + (fc << 4) + l15] = f2bf(acc[fr][fc][rg] * sc);
            }
        // copy: 64 lanes x 16 shorts = 1024 = 32 rows x 32 cols  (checksum OK)
        int rr = lane >> 1, seg = lane & 1;
        int R = rowBaseG + rr;
        if (R < M) {
            const short* sp = &relay[rr * 40 + (seg << 4)];
            short* dp = &outb[((size_t)R << 7) + colBase + (seg << 4)];
            ((uint4*)dp)[0] = ((const uint4*)sp)[0];
            ((uint4*)dp)[1] = ((const uint4*)sp)[1];
        }
        cur ^= 1;
    }
}

// ---------------- aggregation: reads bf16 h, writes interleaved hi/lo ----------------

__device__ inline void addrow(uint4 u, fx2* a) {
    a[0] += (fx2){__builtin_bit_cast(float, u.x << 16),
                  __builtin_bit_cast(float, u.x & 0xFFFF0000u)};
    a[1] += (fx2){__builtin_bit_cast(float, u.y << 16),
                  __builtin_bit_cast(float, u.y & 0xFFFF0000u)};
    a[2] += (fx2){__builtin_bit_cast(float, u.z << 16),
                  __builtin_bit_cast(float, u.z & 0xFFFF0000u)};
    a[3] += (fx2){__builtin_bit_cast(float, u.w << 16),
                  __builtin_bit_cast(float, u.w & 0xFFFF0000u)};
}

__device__ inline void agg_body(const short* __restrict__ h,
                                const int* __restrict__ col,
                                const int* __restrict__ offs,
                                const float* __restrict__ dinv,
                                const float* __restrict__ bias,
                                short* __restrict__ xoI,
                                int v, int orow) {
    int lane = threadIdx.x & 63;
    int g = lane >> 4;
    int li = lane & 15;
    int beg = offs[v], end = offs[v + 1];
    float dv = dinv[v];
    fx2 a4[4] = {{0.f,0.f},{0.f,0.f},{0.f,0.f},{0.f,0.f}};
    if (g == 0)
        addrow(*(const uint4*)&h[(size_t)v * 128 + (li << 3)], a4);
    int e = beg + g;
    for (; e + 12 < end; e += 16) {
        int s0 = col[e], s1 = col[e + 4], s2 = col[e + 8], s3 = col[e + 12];
        uint4 u0 = *(const uint4*)&h[(size_t)s0 * 128 + (li << 3)];
        uint4 u1 = *(const uint4*)&h[(size_t)s1 * 128 + (li << 3)];
        uint4 u2 = *(const uint4*)&h[(size_t)s2 * 128 + (li << 3)];
        uint4 u3 = *(const uint4*)&h[(size_t)s3 * 128 + (li << 3)];
        addrow(u0, a4); addrow(u1, a4); addrow(u2, a4); addrow(u3, a4);
    }
    for (; e < end; e += 4)
        addrow(*(const uint4*)&h[(size_t)col[e] * 128 + (li << 3)], a4);

    float a[8];
#pragma unroll
    for (int j = 0; j < 4; ++j) { a[2 * j] = a4[j][0]; a[2 * j + 1] = a4[j][1]; }
#pragma unroll
    for (int off = 16; off <= 32; off <<= 1)
#pragma unroll
        for (int j = 0; j < 8; ++j) a[j] += __shfl_xor(a[j], off);
    if (g == 0) {
        bf16x8 hh, ll;
#pragma unroll
        for (int j = 0; j < 8; ++j) {
            float o = fmaxf(fmaf(a[j], dv, bias[(li << 3) + j]), 0.f);
            short hb = f2bf(o);
            hh[j] = hb;
            ll[j] = f2bf(o - bf2f(hb));
        }
        short* dst = &xoI[((size_t)orow << 8) + (li << 4)];
        *(bf16x8*)dst = hh;
        *(bf16x8*)(dst + 8) = ll;
    }
}

__global__ __launch_bounds__(256) void k_agg(
    const short* __restrict__ h, const int* __restrict__ col,
    const int* __restrict__ offs, const float* __restrict__ dinv,
    const float* __restrict__ bias, short* __restrict__ xoI, int n) {
    int v = (blockIdx.x << 2) + (threadIdx.x >> 6);
    if (v >= n) return;
    agg_body(h, col, offs, dinv, bias, xoI, v, v);
}

__global__ __launch_bounds__(256) void k_agg3(
    const short* __restrict__ h, const int* __restrict__ col,
    const int* __restrict__ offs, const float* __restrict__ dinv,
    const float* __restrict__ bias, short* __restrict__ xoI,
    const int* __restrict__ sidx, const int* __restrict__ tidx) {
    int i = (blockIdx.x << 2) + (threadIdx.x >> 6);
    if (i >= 2 * BATCH) return;
    int v = (i < BATCH) ? sidx[i] : tidx[i - BATCH];
    agg_body(h, col, offs, dinv, bias, xoI, v, i);
}

// ---------------- fused P/Q projection + dot ----------------
// 512 blocks x 32 pairs; waves 0-1 = P col-halves, waves 2-3 = Q; LDS dot.

__global__ __launch_bounds__(256) void k_pq(
    const short* __restrict__ a1I, const short* __restrict__ a2I,
    const short* __restrict__ x3I, const short* __restrict__ wI,
    const int* __restrict__ sidx, const int* __restrict__ tidx,
    const float* __restrict__ bp, const float* __restrict__ bw,
    float* __restrict__ out) {
    __shared__ float Ps[32][132];
    __shared__ float Qs[32][132];
    int t = threadIdx.x;
    int lane = t & 63, wave = t >> 6;
    int isQ = wave >> 1, wn = wave & 1;
    int l15 = lane & 15;
    int g16 = (lane >> 4) << 4;
    int pairBase = blockIdx.x << 5;
    int colBase = wn << 6;
    const int* gidx = isQ ? tidx : sidx;
    const float* bias = isQ ? bw : bp;
    int r0i = pairBase + l15;
    int r1i = r0i + 16;
    long long n0 = (long long)gidx[r0i];
    long long n1 = (long long)gidx[r1i];

    fx4 acc[2][4];
#pragma unroll
    for (int i = 0; i < 2; ++i)
#pragma unroll
        for (int j = 0; j < 4; ++j) {
            acc[i][j][0] = 0.f; acc[i][j][1] = 0.f;
            acc[i][j][2] = 0.f; acc[i][j][3] = 0.f;
        }

#pragma unroll
    for (int c = 0; c < 3; ++c) {
        const short* AI = (c == 0) ? a1I : (c == 1) ? a2I : x3I;
        long long b0 = (c == 2) ? (long long)(r0i + (isQ << 14)) : n0;
        long long b1 = (c == 2) ? (long long)(r1i + (isQ << 14)) : n1;
        const short* WB = wI + (size_t)(3 + isQ * 3 + c) * 32768;
#pragma unroll
        for (int ks = 0; ks < 4; ++ks) {
            int co = (ks << 6) + g16;
            const short* ap0 = &AI[(b0 << 8) + co];
            const short* ap1 = &AI[(b1 << 8) + co];
            bf16x8 a0h = *(const bf16x8*)ap0;
            bf16x8 a0l = *(const bf16x8*)(ap0 + 8);
            bf16x8 a1h = *(const bf16x8*)ap1;
            bf16x8 a1l = *(const bf16x8*)(ap1 + 8);
#pragma unroll
            for (int fc = 0; fc < 4; ++fc) {
                int cc = colBase + (fc << 4) + l15;
                const short* bpp = &WB[((size_t)cc << 8) + co];
                bf16x8 bh = *(const bf16x8*)bpp;
                bf16x8 bl = *(const bf16x8*)(bpp + 8);
                acc[0][fc] = __builtin_amdgcn_mfma_f32_16x16x32_bf16(a0h, bh, acc[0][fc], 0, 0, 0);
                acc[0][fc] = __builtin_amdgcn_mfma_f32_16x16x32_bf16(a0h, bl, acc[0][fc], 0, 0, 0);
                acc[0][fc] = __builtin_amdgcn_mfma_f32_16x16x32_bf16(a0l, bh, acc[0][fc], 0, 0, 0);
                acc[1][fc] = __builtin_amdgcn_mfma_f32_16x16x32_bf16(a1h, bh, acc[1][fc], 0, 0, 0);
                acc[1][fc] = __builtin_amdgcn_mfma_f32_16x16x32_bf16(a1h, bl, acc[1][fc], 0, 0, 0);
                acc[1][fc] = __builtin_amdgcn_mfma_f32_16x16x32_bf16(a1l, bh, acc[1][fc], 0, 0, 0);
            }
        }
    }

    int rq = (lane >> 4) << 2;
    float (*dst)[132] = isQ ? Qs : Ps;
#pragma unroll
    for (int fr = 0; fr < 2; ++fr) {
#pragma unroll
        for (int fc = 0; fc < 4; ++fc) {
            int cg = colBase + (fc << 4) + l15;
            float bv = bias[cg];
#pragma unroll
            for (int rg = 0; rg < 4; ++rg)
                dst[(fr << 4) + rq + rg][cg] = acc[fr][fc][rg] + bv;
        }
    }
    __syncthreads();

    int p = t >> 3, seg = t & 7;
    const float* pr = &Ps[p][seg * 16];
    const float* qr = &Qs[p][seg * 16];
    float s = 0.f;
#pragma unroll
    for (int j = 0; j < 16; ++j) s += pr[j] * qr[j];
    s += __shfl_xor(s, 1);
    s += __shfl_xor(s, 2);
    s += __shfl_xor(s, 4);
    if (seg == 0) out[pairBase + p] = s;
}

// ---------------- launch ----------------

extern "C" void kernel_launch(void* const* d_in, const int* in_sizes, int n_in,
                              void* d_out, int out_size, void* d_ws, size_t ws_size,
                              hipStream_t stream) {
    const float* x    = (const float*)d_in[0];
    const int*   edge = (const int*)d_in[1];
    const int*   sidx = (const int*)d_in[2];
    const int*   tidx = (const int*)d_in[3];
    const float* Wc0  = (const float*)d_in[4];
    const float* bc0  = (const float*)d_in[5];
    const float* Wc1  = (const float*)d_in[6];
    const float* bc1  = (const float*)d_in[7];
    const float* Wc2  = (const float*)d_in[8];
    const float* bc2  = (const float*)d_in[9];
    const float* Ww   = (const float*)d_in[10];
    const float* bw   = (const float*)d_in[11];
    const float* Wp   = (const float*)d_in[12];
    const float* bp   = (const float*)d_in[13];
    float* out = (float*)d_out;

    char* base = (char*)d_ws;
    size_t off = 0;
    auto alloc = [&](size_t bytes) -> char* {
        char* p = base + off;
        off = (off + bytes + 255) & ~(size_t)255;
        return p;
    };
    const size_t ISZ = (size_t)N_NODES * 256 * sizeof(short);      // 51.2 MB
    const size_t XSZ = (size_t)2 * BATCH * 256 * sizeof(short);    // 16.8 MB
    short* a1I  = (short*)alloc(ISZ);
    short* a2I  = (short*)alloc(ISZ);
    short* x3I  = (short*)alloc(XSZ);
    short* hbf  = (short*)alloc((size_t)N_NODES * HID * sizeof(short));
    int*   offsets = (int*)alloc((size_t)(N_NODES + 1) * sizeof(int));
    int*   colArr  = (int*)alloc((size_t)N_EDGES * sizeof(int));
    unsigned* tmp  = (unsigned*)alloc((size_t)N_EDGES * sizeof(unsigned));
    float* dinv    = (float*)alloc((size_t)N_NODES * sizeof(float));
    int*   bcnt    = (int*)alloc(256 * sizeof(int));
    int*   bbase   = (int*)alloc(256 * sizeof(int));
    int*   bcur    = (int*)alloc(256 * sizeof(int));
    short* wI      = (short*)alloc((size_t)9 * 32768 * sizeof(short));
    (void)ws_size; (void)in_sizes; (void)n_in; (void)out_size;

    // ---- CSR build ----
    hipMemsetAsync(bcnt, 0, NB * sizeof(int), stream);
    k_bhist<<<(N_EDGES + 4095) / 4096, 256, 0, stream>>>(edge + N_EDGES, bcnt, N_EDGES);
    k_bscan<<<1, 256, 0, stream>>>(bcnt, bbase, bcur, offsets);
    k_passA<<<(N_EDGES + EPB - 1) / EPB, 256, 0, stream>>>(edge, bcur, tmp, N_EDGES);
    k_passB<<<NB, 256, 0, stream>>>(tmp, bbase, offsets, dinv, colArr);

    // ---- weight prep ----
    k_prepW<<<9, 256, 0, stream>>>(Wc0, Wc1, Wc2, Wp, Ww, wI);

    const int aggGrid  = (N_NODES + 3) / 4;    // 25000
    const int agg3Grid = (2 * BATCH) / 4;      // 8192
    const int gemmGrid = 768;                  // persistent, ~3 blocks/CU
#define WI(c) (wI + (size_t)(c) * 32768)

    // ---- layer 1 ----
    k_sgemm<1><<<gemmGrid, 256, 0, stream>>>((const char*)x, WI(0), hbf, dinv, N_NODES);
    k_agg<<<aggGrid, 256, 0, stream>>>(hbf, colArr, offsets, dinv, bc0, a1I, N_NODES);

    // ---- layer 2 ----
    k_sgemm<0><<<gemmGrid, 256, 0, stream>>>((const char*)a1I, WI(1), hbf, dinv, N_NODES);
    k_agg<<<aggGrid, 256, 0, stream>>>(hbf, colArr, offsets, dinv, bc1, a2I, N_NODES);

    // ---- layer 3 (batch nodes only) ----
    k_sgemm<0><<<gemmGrid, 256, 0, stream>>>((const char*)a2I, WI(2), hbf, dinv, N_NODES);
    k_agg3<<<agg3Grid, 256, 0, stream>>>(hbf, colArr, offsets, dinv, bc2, x3I, sidx, tidx);

    // ---- fused P/Q + dot ----
    k_pq<<<BATCH / 32, 256, 0, stream>>>(a1I, a2I, x3I, wI, sidx, tidx, bp, bw, out);
}

// Round 14
// 350.243 us; speedup vs baseline: 1.4170x; 1.0531x over previous
//
#include <hip/hip_runtime.h>
#include <hip/hip_bf16.h>

#define N_NODES 100000
#define N_EDGES 1600000
#define BATCH   16384
#define HID     128

#define SHIFT 9
#define BSZ   512
#define NB    196
#define EPB   8192
#define CAP   10240   // fixed bucket capacity (mean 8163, sd 90 -> 23 sigma margin)

typedef __attribute__((ext_vector_type(8))) short bf16x8;
typedef __attribute__((ext_vector_type(4))) float fx4;
typedef __attribute__((ext_vector_type(2))) float fx2;

__device__ inline short f2bf(float f) {
    unsigned u = __builtin_bit_cast(unsigned, f);
    unsigned r = (u + 0x7FFF + ((u >> 16) & 1)) >> 16;
    return (short)r;
}
__device__ inline float bf2f(short s) {
    unsigned u = ((unsigned)(unsigned short)s) << 16;
    return __builtin_bit_cast(float, u);
}

// barrier without vmcnt drain; fenced against compiler reordering (rule #18)
#define RAW_BARRIER() do { \
    __builtin_amdgcn_sched_barrier(0); \
    asm volatile("" ::: "memory"); \
    __builtin_amdgcn_s_barrier(); \
    __builtin_amdgcn_sched_barrier(0); \
} while (0)

// ---------------- CSR build: fixed-capacity buckets, two kernels ----------------

__global__ __launch_bounds__(256) void k_passA(
    const int* __restrict__ edge, int* __restrict__ bcur,
    unsigned* __restrict__ tmp, int E) {
    __shared__ unsigned staged[EPB];
    __shared__ unsigned char bkt[EPB];
    __shared__ int lh[NB], lstart[NB], gbase[NB], lcur[NB];
    int t = threadIdx.x;
    int base = blockIdx.x * EPB;
    int n = min(EPB, E - base);
    for (int j = t; j < NB; j += 256) lh[j] = 0;
    __syncthreads();
    for (int i = t; i < n; i += 256)
        atomicAdd(&lh[edge[E + base + i] >> SHIFT], 1);
    __syncthreads();
    if (t == 0) {
        int run = 0;
        for (int b = 0; b < NB; ++b) { lstart[b] = run; run += lh[b]; }
    }
    __syncthreads();
    if (t < NB) {
        gbase[t] = atomicAdd(&bcur[t], lh[t]);
        lcur[t] = lstart[t];
    }
    __syncthreads();
    for (int i = t; i < n; i += 256) {
        int s = edge[base + i];
        int d = edge[E + base + i];
        int b = d >> SHIFT;
        unsigned p = (unsigned)s | ((unsigned)(d & (BSZ - 1)) << 17);
        int pos = atomicAdd(&lcur[b], 1);
        staged[pos] = p;
        bkt[pos] = (unsigned char)b;
    }
    __syncthreads();
    for (int i = t; i < n; i += 256) {
        int b = bkt[i];
        tmp[(size_t)b * CAP + gbase[b] + (i - lstart[b])] = staged[i];
    }
}

__global__ __launch_bounds__(256) void k_passB(
    const unsigned* __restrict__ tmp, const int* __restrict__ bcur,
    int* __restrict__ offsets, int* __restrict__ ends,
    float* __restrict__ dinv, int* __restrict__ col) {
    __shared__ int lh[BSZ];
    __shared__ int lsum[256];
    int b = blockIdx.x, t = threadIdx.x;
    int begin = b * CAP;
    int end = begin + bcur[b];
    lh[t] = 0; lh[t + 256] = 0;
    __syncthreads();
    for (int i = begin + t; i < end; i += 256)
        atomicAdd(&lh[tmp[i] >> 17], 1);
    __syncthreads();
    int c0 = lh[2 * t], c1 = lh[2 * t + 1];
    int tsum = c0 + c1;
    lsum[t] = tsum;
    __syncthreads();
    for (int off = 1; off < 256; off <<= 1) {
        int v = 0;
        if (t >= off) v = lsum[t - off];
        __syncthreads();
        if (t >= off) lsum[t] += v;
        __syncthreads();
    }
    int texcl = lsum[t] - tsum;
    int node0 = (b << SHIFT) + 2 * t;
    if (node0 < N_NODES) {
        offsets[node0] = begin + texcl;
        ends[node0] = begin + texcl + c0;
        dinv[node0] = rsqrtf((float)c0 + 1.f);
    }
    if (node0 + 1 < N_NODES) {
        offsets[node0 + 1] = begin + texcl + c0;
        ends[node0 + 1] = begin + texcl + c0 + c1;
        dinv[node0 + 1] = rsqrtf((float)c1 + 1.f);
    }
    __syncthreads();
    lh[2 * t] = texcl;
    lh[2 * t + 1] = texcl + c0;
    __syncthreads();
    for (int i = begin + t; i < end; i += 1024) {
        int i1 = i + 256, i2 = i + 512, i3 = i + 768;
        unsigned p0 = tmp[i];
        unsigned p1 = (i1 < end) ? tmp[i1] : 0u;
        unsigned p2 = (i2 < end) ? tmp[i2] : 0u;
        unsigned p3 = (i3 < end) ? tmp[i3] : 0u;
        int q0 = begin + atomicAdd(&lh[p0 >> 17], 1);
        col[q0] = (int)(p0 & 0x1FFFFu);
        if (i1 < end) { int q = begin + atomicAdd(&lh[p1 >> 17], 1); col[q] = (int)(p1 & 0x1FFFFu); }
        if (i2 < end) { int q = begin + atomicAdd(&lh[p2 >> 17], 1); col[q] = (int)(p2 & 0x1FFFFu); }
        if (i3 < end) { int q = begin + atomicAdd(&lh[p3 >> 17], 1); col[q] = (int)(p3 & 0x1FFFFu); }
    }
}

// ---------------- weight prep: fp32 W[k][n] -> interleaved hi/lo, transposed ----------------

__global__ void k_prepW(const float* __restrict__ Wc0, const float* __restrict__ Wc1,
                        const float* __restrict__ Wc2, const float* __restrict__ Wp,
                        const float* __restrict__ Ww, short* __restrict__ wI) {
    int c = blockIdx.x;
    const float* src;
    int koff = 0;
    if (c == 0) src = Wc0;
    else if (c == 1) src = Wc1;
    else if (c == 2) src = Wc2;
    else if (c < 6) { src = Wp; koff = (c - 3) * 128; }
    else { src = Ww; koff = (c - 6) * 128; }
    short* d = wI + (size_t)c * 32768;
    for (int i = threadIdx.x; i < 16384; i += 256) {
        int k = i >> 7, n = i & 127;
        float v = src[(size_t)(koff + k) * 128 + n];
        short h = f2bf(v);
        short l = f2bf(v - bf2f(h));
        int c16 = k >> 3, j = k & 7;
        d[n * 256 + c16 * 16 + j] = h;
        d[n * 256 + c16 * 16 + 8 + j] = l;
    }
}

// ---------------- deep-pipelined persistent GEMM (T3/T4 counted vmcnt) ----------------
// A row = 512 B (fp32 x OR interleaved bf16 hi/lo). Tile = 32 rows = 16 KB.
// 4 LDS buffers, 3 stages in flight, counted s_waitcnt vmcnt(N) (never 0 in loop).
// Per-wave vmem ops/iter: exactly 4 stage loads + 2 epilogue stores (no scale!).
// 4 waves; wave = 32 rows x 32 cols; B (32 cols, interleaved) in registers.

__device__ inline void stage_tile(char* __restrict__ buf, const char* __restrict__ A,
                                  int tile, int maxRow, int t) {
    int rowBase = tile << 5;
#pragma unroll
    for (int j = 0; j < 4; ++j) {
        int s = (j << 8) + t;            // 16B slot 0..1023
        int row = s >> 5;
        int cpos = s & 31;
        int c = cpos ^ (row & 7);        // pre-swizzled source chunk
        int gr = rowBase + row;
        if (gr > maxRow) gr = maxRow;    // clamps dummy/tail tiles too
        const char* src = A + ((size_t)gr << 9) + (c << 4);
        char* dst = buf + (((j << 8) + (t & 192)) << 4);   // wave-uniform base
        __builtin_amdgcn_global_load_lds(
            (const __attribute__((address_space(1))) unsigned*)src,
            (__attribute__((address_space(3))) unsigned*)dst, 16, 0, 0);
    }
}

template<int ISF32>
__global__ __launch_bounds__(256) void k_sgemm(
    const char* __restrict__ A, const short* __restrict__ WI,
    short* __restrict__ outb, int M) {
    __shared__ __align__(16) char lds[65536];
    int t = threadIdx.x;
    int lane = t & 63, wave = t >> 6;
    int l15 = lane & 15, g = lane >> 4;
    int colBase = wave << 5;
    int rq = g << 2;

    // ---- B into registers (once): this wave's 32 cols ----
    bf16x8 Bh[4][2], Bl[4][2];
#pragma unroll
    for (int ks = 0; ks < 4; ++ks)
#pragma unroll
        for (int fc = 0; fc < 2; ++fc) {
            int c = colBase + (fc << 4) + l15;
            const short* bp = &WI[((size_t)c << 8) + (((ks << 2) + g) << 4)];
            Bh[ks][fc] = *(const bf16x8*)bp;
            Bl[ks][fc] = *(const bf16x8*)(bp + 8);
        }

    int nT = (M + 31) >> 5;
    int maxRow = M - 1;
    int grid = (int)gridDim.x;
    int tile = blockIdx.x;
    if (tile >= nT) return;

    // ---- prologue: 3 stages in flight (12 loads/wave) ----
    stage_tile(lds,             A, tile,            maxRow, t);
    stage_tile(lds + (1 << 14), A, tile + grid,     maxRow, t);
    stage_tile(lds + (2 << 14), A, tile + 2 * grid, maxRow, t);

    int iter = 0;
    for (; tile < nT; tile += grid, ++iter) {
        // wait: oldest stage landed. Accounting per wave (issue order):
        // P:[4,4,4]  I_k:[2 stores][4 loads]  => waits 8,10,12,12,...
        if (iter == 0)      asm volatile("s_waitcnt vmcnt(8)" ::: "memory");
        else if (iter == 1) asm volatile("s_waitcnt vmcnt(10)" ::: "memory");
        else                asm volatile("s_waitcnt vmcnt(12)" ::: "memory");
        RAW_BARRIER();

        char* buf = lds + ((iter & 3) << 14);

        fx4 acc[2][2];
#pragma unroll
        for (int i = 0; i < 2; ++i)
#pragma unroll
            for (int j = 0; j < 2; ++j) {
                acc[i][j][0] = 0.f; acc[i][j][1] = 0.f;
                acc[i][j][2] = 0.f; acc[i][j][3] = 0.f;
            }

#pragma unroll
        for (int ks = 0; ks < 4; ++ks) {
            bf16x8 ah[2], al[2];
#pragma unroll
            for (int fr = 0; fr < 2; ++fr) {
                int row = (fr << 4) + l15;
                int c0 = (ks << 3) + (g << 1);
                const char* p0 = buf + (row << 9) + ((c0 ^ (row & 7)) << 4);
                const char* p1 = buf + (row << 9) + (((c0 + 1) ^ (row & 7)) << 4);
                if (ISF32) {
                    float v[8];
                    *(float4*)&v[0] = *(const float4*)p0;
                    *(float4*)&v[4] = *(const float4*)p1;
#pragma unroll
                    for (int j = 0; j < 8; ++j) {
                        short hb = f2bf(v[j]);
                        ah[fr][j] = hb;
                        al[fr][j] = f2bf(v[j] - bf2f(hb));
                    }
                } else {
                    ah[fr] = *(const bf16x8*)p0;
                    al[fr] = *(const bf16x8*)p1;
                }
            }
#pragma unroll
            for (int fc = 0; fc < 2; ++fc) {
                acc[0][fc] = __builtin_amdgcn_mfma_f32_16x16x32_bf16(ah[0], Bh[ks][fc], acc[0][fc], 0, 0, 0);
                acc[0][fc] = __builtin_amdgcn_mfma_f32_16x16x32_bf16(ah[0], Bl[ks][fc], acc[0][fc], 0, 0, 0);
                acc[0][fc] = __builtin_amdgcn_mfma_f32_16x16x32_bf16(al[0], Bh[ks][fc], acc[0][fc], 0, 0, 0);
                acc[1][fc] = __builtin_amdgcn_mfma_f32_16x16x32_bf16(ah[1], Bh[ks][fc], acc[1][fc], 0, 0, 0);
                acc[1][fc] = __builtin_amdgcn_mfma_f32_16x16x32_bf16(ah[1], Bl[ks][fc], acc[1][fc], 0, 0, 0);
                acc[1][fc] = __builtin_amdgcn_mfma_f32_16x16x32_bf16(al[1], Bh[ks][fc], acc[1][fc], 0, 0, 0);
            }
        }

        RAW_BARRIER();   // all waves done reading buf A-frags; slot reusable as relay

        // ---- epilogue: relay via this wave's quarter of buf (no scale) ----
        short* relay = (short*)buf + wave * 2048;    // 4096 B/wave, uses 2560 B
        int rowBaseG = tile << 5;
#pragma unroll
        for (int fr = 0; fr < 2; ++fr)
#pragma unroll
            for (int rg = 0; rg < 4; ++rg) {
                int rl = (fr << 4) + rq + rg;
#pragma unroll
                for (int fc = 0; fc < 2; ++fc)
                    relay[rl * 40 + (fc << 4) + l15] = f2bf(acc[fr][fc][rg]);
            }
        int rr = lane >> 1, seg = lane & 1;
        int R = rowBaseG + rr;
        if (R < M) {
            const short* sp = &relay[rr * 40 + (seg << 4)];
            short* dp = &outb[((size_t)R << 7) + colBase + (seg << 4)];
            ((uint4*)dp)[0] = ((const uint4*)sp)[0];
            ((uint4*)dp)[1] = ((const uint4*)sp)[1];
        }

        // ---- issue stage for tile+3 (dummy-clamped: keeps vmcnt accounting) ----
        __builtin_amdgcn_sched_barrier(0);
        stage_tile(lds + (((iter + 3) & 3) << 14), A, tile + 3 * grid, maxRow, t);
    }
    // drain before endpgm: outstanding global_load_lds must not write freed LDS
    asm volatile("s_waitcnt vmcnt(0)" ::: "memory");
}

// ---------------- aggregation: consumer-side dinv, writes interleaved hi/lo ----------------
// o[v] = relu(dinv[v]*(sum_e dinv[col[e]]*h[col[e]] + dinv[v]*h[v]) + bias)

__device__ inline void addrow(uint4 u, float d, fx2* a) {
    a[0][0] = fmaf(__builtin_bit_cast(float, u.x << 16), d, a[0][0]);
    a[0][1] = fmaf(__builtin_bit_cast(float, u.x & 0xFFFF0000u), d, a[0][1]);
    a[1][0] = fmaf(__builtin_bit_cast(float, u.y << 16), d, a[1][0]);
    a[1][1] = fmaf(__builtin_bit_cast(float, u.y & 0xFFFF0000u), d, a[1][1]);
    a[2][0] = fmaf(__builtin_bit_cast(float, u.z << 16), d, a[2][0]);
    a[2][1] = fmaf(__builtin_bit_cast(float, u.z & 0xFFFF0000u), d, a[2][1]);
    a[3][0] = fmaf(__builtin_bit_cast(float, u.w << 16), d, a[3][0]);
    a[3][1] = fmaf(__builtin_bit_cast(float, u.w & 0xFFFF0000u), d, a[3][1]);
}

__device__ inline void agg_body(const short* __restrict__ h,
                                const int* __restrict__ col,
                                const int* __restrict__ offs,
                                const int* __restrict__ ends,
                                const float* __restrict__ dinv,
                                const float* __restrict__ bias,
                                short* __restrict__ xoI,
                                int v, int orow) {
    int lane = threadIdx.x & 63;
    int g = lane >> 4;
    int li = lane & 15;
    int beg = offs[v], end = ends[v];
    float dv = dinv[v];
    fx2 a4[4] = {{0.f,0.f},{0.f,0.f},{0.f,0.f},{0.f,0.f}};
    if (g == 0)
        addrow(*(const uint4*)&h[(size_t)v * 128 + (li << 3)], dv, a4);
    int e = beg + g;
    for (; e + 12 < end; e += 16) {
        int s0 = col[e], s1 = col[e + 4], s2 = col[e + 8], s3 = col[e + 12];
        float d0 = dinv[s0], d1 = dinv[s1], d2 = dinv[s2], d3 = dinv[s3];
        uint4 u0 = *(const uint4*)&h[(size_t)s0 * 128 + (li << 3)];
        uint4 u1 = *(const uint4*)&h[(size_t)s1 * 128 + (li << 3)];
        uint4 u2 = *(const uint4*)&h[(size_t)s2 * 128 + (li << 3)];
        uint4 u3 = *(const uint4*)&h[(size_t)s3 * 128 + (li << 3)];
        addrow(u0, d0, a4); addrow(u1, d1, a4);
        addrow(u2, d2, a4); addrow(u3, d3, a4);
    }
    for (; e < end; e += 4) {
        int s = col[e];
        addrow(*(const uint4*)&h[(size_t)s * 128 + (li << 3)], dinv[s], a4);
    }

    float a[8];
#pragma unroll
    for (int j = 0; j < 4; ++j) { a[2 * j] = a4[j][0]; a[2 * j + 1] = a4[j][1]; }
#pragma unroll
    for (int off = 16; off <= 32; off <<= 1)
#pragma unroll
        for (int j = 0; j < 8; ++j) a[j] += __shfl_xor(a[j], off);
    if (g == 0) {
        bf16x8 hh, ll;
#pragma unroll
        for (int j = 0; j < 8; ++j) {
            float o = fmaxf(fmaf(a[j], dv, bias[(li << 3) + j]), 0.f);
            short hb = f2bf(o);
            hh[j] = hb;
            ll[j] = f2bf(o - bf2f(hb));
        }
        short* dst = &xoI[((size_t)orow << 8) + (li << 4)];
        *(bf16x8*)dst = hh;
        *(bf16x8*)(dst + 8) = ll;
    }
}

__global__ __launch_bounds__(256) void k_agg(
    const short* __restrict__ h, const int* __restrict__ col,
    const int* __restrict__ offs, const int* __restrict__ ends,
    const float* __restrict__ dinv, const float* __restrict__ bias,
    short* __restrict__ xoI, int n) {
    int v = (blockIdx.x << 2) + (threadIdx.x >> 6);
    if (v >= n) return;
    agg_body(h, col, offs, ends, dinv, bias, xoI, v, v);
}

__global__ __launch_bounds__(256) void k_agg3(
    const short* __restrict__ h, const int* __restrict__ col,
    const int* __restrict__ offs, const int* __restrict__ ends,
    const float* __restrict__ dinv, const float* __restrict__ bias,
    short* __restrict__ xoI, const int* __restrict__ sidx,
    const int* __restrict__ tidx) {
    int i = (blockIdx.x << 2) + (threadIdx.x >> 6);
    if (i >= 2 * BATCH) return;
    int v = (i < BATCH) ? sidx[i] : tidx[i - BATCH];
    agg_body(h, col, offs, ends, dinv, bias, xoI, v, i);
}

// ---------------- fused P/Q projection + dot (unchanged) ----------------

__global__ __launch_bounds__(256) void k_pq(
    const short* __restrict__ a1I, const short* __restrict__ a2I,
    const short* __restrict__ x3I, const short* __restrict__ wI,
    const int* __restrict__ sidx, const int* __restrict__ tidx,
    const float* __restrict__ bp, const float* __restrict__ bw,
    float* __restrict__ out) {
    __shared__ float Ps[32][132];
    __shared__ float Qs[32][132];
    int t = threadIdx.x;
    int lane = t & 63, wave = t >> 6;
    int isQ = wave >> 1, wn = wave & 1;
    int l15 = lane & 15;
    int g16 = (lane >> 4) << 4;
    int pairBase = blockIdx.x << 5;
    int colBase = wn << 6;
    const int* gidx = isQ ? tidx : sidx;
    const float* bias = isQ ? bw : bp;
    int r0i = pairBase + l15;
    int r1i = r0i + 16;
    long long n0 = (long long)gidx[r0i];
    long long n1 = (long long)gidx[r1i];

    fx4 acc[2][4];
#pragma unroll
    for (int i = 0; i < 2; ++i)
#pragma unroll
        for (int j = 0; j < 4; ++j) {
            acc[i][j][0] = 0.f; acc[i][j][1] = 0.f;
            acc[i][j][2] = 0.f; acc[i][j][3] = 0.f;
        }

#pragma unroll
    for (int c = 0; c < 3; ++c) {
        const short* AI = (c == 0) ? a1I : (c == 1) ? a2I : x3I;
        long long b0 = (c == 2) ? (long long)(r0i + (isQ << 14)) : n0;
        long long b1 = (c == 2) ? (long long)(r1i + (isQ << 14)) : n1;
        const short* WB = wI + (size_t)(3 + isQ * 3 + c) * 32768;
#pragma unroll
        for (int ks = 0; ks < 4; ++ks) {
            int co = (ks << 6) + g16;
            const short* ap0 = &AI[(b0 << 8) + co];
            const short* ap1 = &AI[(b1 << 8) + co];
            bf16x8 a0h = *(const bf16x8*)ap0;
            bf16x8 a0l = *(const bf16x8*)(ap0 + 8);
            bf16x8 a1h = *(const bf16x8*)ap1;
            bf16x8 a1l = *(const bf16x8*)(ap1 + 8);
#pragma unroll
            for (int fc = 0; fc < 4; ++fc) {
                int cc = colBase + (fc << 4) + l15;
                const short* bpp = &WB[((size_t)cc << 8) + co];
                bf16x8 bh = *(const bf16x8*)bpp;
                bf16x8 bl = *(const bf16x8*)(bpp + 8);
                acc[0][fc] = __builtin_amdgcn_mfma_f32_16x16x32_bf16(a0h, bh, acc[0][fc], 0, 0, 0);
                acc[0][fc] = __builtin_amdgcn_mfma_f32_16x16x32_bf16(a0h, bl, acc[0][fc], 0, 0, 0);
                acc[0][fc] = __builtin_amdgcn_mfma_f32_16x16x32_bf16(a0l, bh, acc[0][fc], 0, 0, 0);
                acc[1][fc] = __builtin_amdgcn_mfma_f32_16x16x32_bf16(a1h, bh, acc[1][fc], 0, 0, 0);
                acc[1][fc] = __builtin_amdgcn_mfma_f32_16x16x32_bf16(a1h, bl, acc[1][fc], 0, 0, 0);
                acc[1][fc] = __builtin_amdgcn_mfma_f32_16x16x32_bf16(a1l, bh, acc[1][fc], 0, 0, 0);
            }
        }
    }

    int rq = (lane >> 4) << 2;
    float (*dst)[132] = isQ ? Qs : Ps;
#pragma unroll
    for (int fr = 0; fr < 2; ++fr) {
#pragma unroll
        for (int fc = 0; fc < 4; ++fc) {
            int cg = colBase + (fc << 4) + l15;
            float bv = bias[cg];
#pragma unroll
            for (int rg = 0; rg < 4; ++rg)
                dst[(fr << 4) + rq + rg][cg] = acc[fr][fc][rg] + bv;
        }
    }
    __syncthreads();

    int p = t >> 3, seg = t & 7;
    const float* pr = &Ps[p][seg * 16];
    const float* qr = &Qs[p][seg * 16];
    float s = 0.f;
#pragma unroll
    for (int j = 0; j < 16; ++j) s += pr[j] * qr[j];
    s += __shfl_xor(s, 1);
    s += __shfl_xor(s, 2);
    s += __shfl_xor(s, 4);
    if (seg == 0) out[pairBase + p] = s;
}

// ---------------- launch ----------------

extern "C" void kernel_launch(void* const* d_in, const int* in_sizes, int n_in,
                              void* d_out, int out_size, void* d_ws, size_t ws_size,
                              hipStream_t stream) {
    const float* x    = (const float*)d_in[0];
    const int*   edge = (const int*)d_in[1];
    const int*   sidx = (const int*)d_in[2];
    const int*   tidx = (const int*)d_in[3];
    const float* Wc0  = (const float*)d_in[4];
    const float* bc0  = (const float*)d_in[5];
    const float* Wc1  = (const float*)d_in[6];
    const float* bc1  = (const float*)d_in[7];
    const float* Wc2  = (const float*)d_in[8];
    const float* bc2  = (const float*)d_in[9];
    const float* Ww   = (const float*)d_in[10];
    const float* bw   = (const float*)d_in[11];
    const float* Wp   = (const float*)d_in[12];
    const float* bp   = (const float*)d_in[13];
    float* out = (float*)d_out;

    char* base = (char*)d_ws;
    size_t off = 0;
    auto alloc = [&](size_t bytes) -> char* {
        char* p = base + off;
        off = (off + bytes + 255) & ~(size_t)255;
        return p;
    };
    const size_t ISZ = (size_t)N_NODES * 256 * sizeof(short);      // 51.2 MB
    const size_t XSZ = (size_t)2 * BATCH * 256 * sizeof(short);    // 16.8 MB
    short* a1I  = (short*)alloc(ISZ);
    short* a2I  = (short*)alloc(ISZ);
    short* x3I  = (short*)alloc(XSZ);
    short* hbf  = (short*)alloc((size_t)N_NODES * HID * sizeof(short));
    int*   offsets = (int*)alloc((size_t)N_NODES * sizeof(int));
    int*   endsA   = (int*)alloc((size_t)N_NODES * sizeof(int));
    int*   colArr  = (int*)alloc((size_t)NB * CAP * sizeof(int));
    unsigned* tmp  = (unsigned*)alloc((size_t)NB * CAP * sizeof(unsigned));
    float* dinv    = (float*)alloc((size_t)N_NODES * sizeof(float));
    int*   bcur    = (int*)alloc(256 * sizeof(int));
    short* wI      = (short*)alloc((size_t)9 * 32768 * sizeof(short));
    (void)ws_size; (void)in_sizes; (void)n_in; (void)out_size;

    // ---- CSR build (fixed-capacity buckets) ----
    hipMemsetAsync(bcur, 0, NB * sizeof(int), stream);
    k_passA<<<(N_EDGES + EPB - 1) / EPB, 256, 0, stream>>>(edge, bcur, tmp, N_EDGES);
    k_passB<<<NB, 256, 0, stream>>>(tmp, bcur, offsets, endsA, dinv, colArr);

    // ---- weight prep ----
    k_prepW<<<9, 256, 0, stream>>>(Wc0, Wc1, Wc2, Wp, Ww, wI);

    const int aggGrid  = (N_NODES + 3) / 4;    // 25000
    const int agg3Grid = (2 * BATCH) / 4;      // 8192
    const int gemmGrid = 512;                  // persistent, 2 blocks/CU, ~6 tiles each
#define WI(c) (wI + (size_t)(c) * 32768)

    // ---- layer 1 ----
    k_sgemm<1><<<gemmGrid, 256, 0, stream>>>((const char*)x, WI(0), hbf, N_NODES);
    k_agg<<<aggGrid, 256, 0, stream>>>(hbf, colArr, offsets, endsA, dinv, bc0, a1I, N_NODES);

    // ---- layer 2 ----
    k_sgemm<0><<<gemmGrid, 256, 0, stream>>>((const char*)a1I, WI(1), hbf, N_NODES);
    k_agg<<<aggGrid, 256, 0, stream>>>(hbf, colArr, offsets, endsA, dinv, bc1, a2I, N_NODES);

    // ---- layer 3 (batch nodes only) ----
    k_sgemm<0><<<gemmGrid, 256, 0, stream>>>((const char*)a2I, WI(2), hbf, N_NODES);
    k_agg3<<<agg3Grid, 256, 0, stream>>>(hbf, colArr, offsets, endsA, dinv, bc2, x3I, sidx, tidx);

    // ---- fused P/Q + dot ----
    k_pq<<<BATCH / 32, 256, 0, stream>>>(a1I, a2I, x3I, wI, sidx, tidx, bp, bw, out);
}

// Round 15
// 332.315 us; speedup vs baseline: 1.4934x; 1.0539x over previous
//
#include <hip/hip_runtime.h>
#include <hip/hip_bf16.h>

#define N_NODES 100000
#define N_EDGES 1600000
#define BATCH   16384
#define HID     128

#define SHIFT 9
#define BSZ   512
#define NB    196
#define EPB   8192
#define PA_BLOCKS 196   // ceil(N_EDGES/EPB)
#define CAP   10240

typedef __attribute__((ext_vector_type(8))) short bf16x8;
typedef __attribute__((ext_vector_type(4))) float fx4;
typedef __attribute__((ext_vector_type(2))) float fx2;

__device__ inline short f2bf(float f) {
    unsigned u = __builtin_bit_cast(unsigned, f);
    unsigned r = (u + 0x7FFF + ((u >> 16) & 1)) >> 16;
    return (short)r;
}
__device__ inline float bf2f(short s) {
    unsigned u = ((unsigned)(unsigned short)s) << 16;
    return __builtin_bit_cast(float, u);
}

#define RAW_BARRIER() do { \
    __builtin_amdgcn_sched_barrier(0); \
    asm volatile("" ::: "memory"); \
    __builtin_amdgcn_s_barrier(); \
    __builtin_amdgcn_sched_barrier(0); \
} while (0)

// ---------------- CSR passA + weight prep (fused) ----------------

__global__ __launch_bounds__(256) void k_passA(
    const int* __restrict__ edge, int* __restrict__ bcur,
    unsigned* __restrict__ tmp, int E,
    const float* __restrict__ Wc0, const float* __restrict__ Wc1,
    const float* __restrict__ Wc2, const float* __restrict__ Wp,
    const float* __restrict__ Ww, short* __restrict__ wI) {
    if (blockIdx.x >= PA_BLOCKS) {
        // ---- weight prep path ----
        int c = blockIdx.x - PA_BLOCKS;
        const float* src;
        int koff = 0;
        if (c == 0) src = Wc0;
        else if (c == 1) src = Wc1;
        else if (c == 2) src = Wc2;
        else if (c < 6) { src = Wp; koff = (c - 3) * 128; }
        else { src = Ww; koff = (c - 6) * 128; }
        short* d = wI + (size_t)c * 32768;
        for (int i = threadIdx.x; i < 16384; i += 256) {
            int k = i >> 7, n = i & 127;
            float v = src[(size_t)(koff + k) * 128 + n];
            short h = f2bf(v);
            short l = f2bf(v - bf2f(h));
            int c16 = k >> 3, j = k & 7;
            d[n * 256 + c16 * 16 + j] = h;
            d[n * 256 + c16 * 16 + 8 + j] = l;
        }
        return;
    }
    __shared__ unsigned staged[EPB];
    __shared__ unsigned char bkt[EPB];
    __shared__ int lh[NB], lstart[NB], gbase[NB], lcur[NB];
    int t = threadIdx.x;
    int base = blockIdx.x * EPB;
    int n = min(EPB, E - base);
    for (int j = t; j < NB; j += 256) lh[j] = 0;
    __syncthreads();
    for (int i = t; i < n; i += 256)
        atomicAdd(&lh[edge[E + base + i] >> SHIFT], 1);
    __syncthreads();
    if (t == 0) {
        int run = 0;
        for (int b = 0; b < NB; ++b) { lstart[b] = run; run += lh[b]; }
    }
    __syncthreads();
    if (t < NB) {
        gbase[t] = atomicAdd(&bcur[t], lh[t]);
        lcur[t] = lstart[t];
    }
    __syncthreads();
    for (int i = t; i < n; i += 256) {
        int s = edge[base + i];
        int d = edge[E + base + i];
        int b = d >> SHIFT;
        unsigned p = (unsigned)s | ((unsigned)(d & (BSZ - 1)) << 17);
        int pos = atomicAdd(&lcur[b], 1);
        staged[pos] = p;
        bkt[pos] = (unsigned char)b;
    }
    __syncthreads();
    for (int i = t; i < n; i += 256) {
        int b = bkt[i];
        tmp[(size_t)b * CAP + gbase[b] + (i - lstart[b])] = staged[i];
    }
}

__global__ __launch_bounds__(256) void k_passB(
    const unsigned* __restrict__ tmp, const int* __restrict__ bcur,
    int* __restrict__ offsets, int* __restrict__ ends,
    float* __restrict__ dinv, int* __restrict__ col) {
    __shared__ int lh[BSZ];
    __shared__ int lsum[256];
    int b = blockIdx.x, t = threadIdx.x;
    int begin = b * CAP;
    int end = begin + bcur[b];
    lh[t] = 0; lh[t + 256] = 0;
    __syncthreads();
    for (int i = begin + t; i < end; i += 256)
        atomicAdd(&lh[tmp[i] >> 17], 1);
    __syncthreads();
    int c0 = lh[2 * t], c1 = lh[2 * t + 1];
    int tsum = c0 + c1;
    lsum[t] = tsum;
    __syncthreads();
    for (int off = 1; off < 256; off <<= 1) {
        int v = 0;
        if (t >= off) v = lsum[t - off];
        __syncthreads();
        if (t >= off) lsum[t] += v;
        __syncthreads();
    }
    int texcl = lsum[t] - tsum;
    int node0 = (b << SHIFT) + 2 * t;
    if (node0 < N_NODES) {
        offsets[node0] = begin + texcl;
        ends[node0] = begin + texcl + c0;
        dinv[node0] = rsqrtf((float)c0 + 1.f);
    }
    if (node0 + 1 < N_NODES) {
        offsets[node0 + 1] = begin + texcl + c0;
        ends[node0 + 1] = begin + texcl + c0 + c1;
        dinv[node0 + 1] = rsqrtf((float)c1 + 1.f);
    }
    __syncthreads();
    lh[2 * t] = texcl;
    lh[2 * t + 1] = texcl + c0;
    __syncthreads();
    for (int i = begin + t; i < end; i += 1024) {
        int i1 = i + 256, i2 = i + 512, i3 = i + 768;
        unsigned p0 = tmp[i];
        unsigned p1 = (i1 < end) ? tmp[i1] : 0u;
        unsigned p2 = (i2 < end) ? tmp[i2] : 0u;
        unsigned p3 = (i3 < end) ? tmp[i3] : 0u;
        int q0 = begin + atomicAdd(&lh[p0 >> 17], 1);
        col[q0] = (int)(p0 & 0x1FFFFu);
        if (i1 < end) { int q = begin + atomicAdd(&lh[p1 >> 17], 1); col[q] = (int)(p1 & 0x1FFFFu); }
        if (i2 < end) { int q = begin + atomicAdd(&lh[p2 >> 17], 1); col[q] = (int)(p2 & 0x1FFFFu); }
        if (i3 < end) { int q = begin + atomicAdd(&lh[p3 >> 17], 1); col[q] = (int)(p3 & 0x1FFFFu); }
    }
}

// ---------------- deep-pipelined persistent GEMM (unchanged from round 14) ----------------

__device__ inline void stage_tile(char* __restrict__ buf, const char* __restrict__ A,
                                  int tile, int maxRow, int t) {
    int rowBase = tile << 5;
#pragma unroll
    for (int j = 0; j < 4; ++j) {
        int s = (j << 8) + t;
        int row = s >> 5;
        int cpos = s & 31;
        int c = cpos ^ (row & 7);
        int gr = rowBase + row;
        if (gr > maxRow) gr = maxRow;
        const char* src = A + ((size_t)gr << 9) + (c << 4);
        char* dst = buf + (((j << 8) + (t & 192)) << 4);
        __builtin_amdgcn_global_load_lds(
            (const __attribute__((address_space(1))) unsigned*)src,
            (__attribute__((address_space(3))) unsigned*)dst, 16, 0, 0);
    }
}

template<int ISF32>
__global__ __launch_bounds__(256) void k_sgemm(
    const char* __restrict__ A, const short* __restrict__ WI,
    short* __restrict__ outb, int M) {
    __shared__ __align__(16) char lds[65536];
    int t = threadIdx.x;
    int lane = t & 63, wave = t >> 6;
    int l15 = lane & 15, g = lane >> 4;
    int colBase = wave << 5;
    int rq = g << 2;

    bf16x8 Bh[4][2], Bl[4][2];
#pragma unroll
    for (int ks = 0; ks < 4; ++ks)
#pragma unroll
        for (int fc = 0; fc < 2; ++fc) {
            int c = colBase + (fc << 4) + l15;
            const short* bp = &WI[((size_t)c << 8) + (((ks << 2) + g) << 4)];
            Bh[ks][fc] = *(const bf16x8*)bp;
            Bl[ks][fc] = *(const bf16x8*)(bp + 8);
        }

    int nT = (M + 31) >> 5;
    int maxRow = M - 1;
    int grid = (int)gridDim.x;
    int tile = blockIdx.x;
    if (tile >= nT) return;

    stage_tile(lds,             A, tile,            maxRow, t);
    stage_tile(lds + (1 << 14), A, tile + grid,     maxRow, t);
    stage_tile(lds + (2 << 14), A, tile + 2 * grid, maxRow, t);

    int iter = 0;
    for (; tile < nT; tile += grid, ++iter) {
        if (iter == 0)      asm volatile("s_waitcnt vmcnt(8)" ::: "memory");
        else if (iter == 1) asm volatile("s_waitcnt vmcnt(10)" ::: "memory");
        else                asm volatile("s_waitcnt vmcnt(12)" ::: "memory");
        RAW_BARRIER();

        char* buf = lds + ((iter & 3) << 14);

        fx4 acc[2][2];
#pragma unroll
        for (int i = 0; i < 2; ++i)
#pragma unroll
            for (int j = 0; j < 2; ++j) {
                acc[i][j][0] = 0.f; acc[i][j][1] = 0.f;
                acc[i][j][2] = 0.f; acc[i][j][3] = 0.f;
            }

#pragma unroll
        for (int ks = 0; ks < 4; ++ks) {
            bf16x8 ah[2], al[2];
#pragma unroll
            for (int fr = 0; fr < 2; ++fr) {
                int row = (fr << 4) + l15;
                int c0 = (ks << 3) + (g << 1);
                const char* p0 = buf + (row << 9) + ((c0 ^ (row & 7)) << 4);
                const char* p1 = buf + (row << 9) + (((c0 + 1) ^ (row & 7)) << 4);
                if (ISF32) {
                    float v[8];
                    *(float4*)&v[0] = *(const float4*)p0;
                    *(float4*)&v[4] = *(const float4*)p1;
#pragma unroll
                    for (int j = 0; j < 8; ++j) {
                        short hb = f2bf(v[j]);
                        ah[fr][j] = hb;
                        al[fr][j] = f2bf(v[j] - bf2f(hb));
                    }
                } else {
                    ah[fr] = *(const bf16x8*)p0;
                    al[fr] = *(const bf16x8*)p1;
                }
            }
#pragma unroll
            for (int fc = 0; fc < 2; ++fc) {
                acc[0][fc] = __builtin_amdgcn_mfma_f32_16x16x32_bf16(ah[0], Bh[ks][fc], acc[0][fc], 0, 0, 0);
                acc[0][fc] = __builtin_amdgcn_mfma_f32_16x16x32_bf16(ah[0], Bl[ks][fc], acc[0][fc], 0, 0, 0);
                acc[0][fc] = __builtin_amdgcn_mfma_f32_16x16x32_bf16(al[0], Bh[ks][fc], acc[0][fc], 0, 0, 0);
                acc[1][fc] = __builtin_amdgcn_mfma_f32_16x16x32_bf16(ah[1], Bh[ks][fc], acc[1][fc], 0, 0, 0);
                acc[1][fc] = __builtin_amdgcn_mfma_f32_16x16x32_bf16(ah[1], Bl[ks][fc], acc[1][fc], 0, 0, 0);
                acc[1][fc] = __builtin_amdgcn_mfma_f32_16x16x32_bf16(al[1], Bh[ks][fc], acc[1][fc], 0, 0, 0);
            }
        }

        RAW_BARRIER();

        short* relay = (short*)buf + wave * 2048;
        int rowBaseG = tile << 5;
#pragma unroll
        for (int fr = 0; fr < 2; ++fr)
#pragma unroll
            for (int rg = 0; rg < 4; ++rg) {
                int rl = (fr << 4) + rq + rg;
#pragma unroll
                for (int fc = 0; fc < 2; ++fc)
                    relay[rl * 40 + (fc << 4) + l15] = f2bf(acc[fr][fc][rg]);
            }
        int rr = lane >> 1, seg = lane & 1;
        int R = rowBaseG + rr;
        if (R < M) {
            const short* sp = &relay[rr * 40 + (seg << 4)];
            short* dp = &outb[((size_t)R << 7) + colBase + (seg << 4)];
            ((uint4*)dp)[0] = ((const uint4*)sp)[0];
            ((uint4*)dp)[1] = ((const uint4*)sp)[1];
        }

        __builtin_amdgcn_sched_barrier(0);
        stage_tile(lds + (((iter + 3) & 3) << 14), A, tile + 3 * grid, maxRow, t);
    }
    asm volatile("s_waitcnt vmcnt(0)" ::: "memory");
}

// ---------------- aggregation: consumer-side dinv, predicated tail ----------------

__device__ inline void addrow(uint4 u, float d, fx2* a) {
    a[0][0] = fmaf(__builtin_bit_cast(float, u.x << 16), d, a[0][0]);
    a[0][1] = fmaf(__builtin_bit_cast(float, u.x & 0xFFFF0000u), d, a[0][1]);
    a[1][0] = fmaf(__builtin_bit_cast(float, u.y << 16), d, a[1][0]);
    a[1][1] = fmaf(__builtin_bit_cast(float, u.y & 0xFFFF0000u), d, a[1][1]);
    a[2][0] = fmaf(__builtin_bit_cast(float, u.z << 16), d, a[2][0]);
    a[2][1] = fmaf(__builtin_bit_cast(float, u.z & 0xFFFF0000u), d, a[2][1]);
    a[3][0] = fmaf(__builtin_bit_cast(float, u.w << 16), d, a[3][0]);
    a[3][1] = fmaf(__builtin_bit_cast(float, u.w & 0xFFFF0000u), d, a[3][1]);
}

__device__ inline void agg_body(const short* __restrict__ h,
                                const int* __restrict__ col,
                                const int* __restrict__ offs,
                                const int* __restrict__ ends,
                                const float* __restrict__ dinv,
                                const float* __restrict__ bias,
                                short* __restrict__ xoI,
                                int v, int orow) {
    int lane = threadIdx.x & 63;
    int g = lane >> 4;
    int li = lane & 15;
    int beg = offs[v], end = ends[v];
    float dv = dinv[v];
    fx2 a4[4] = {{0.f,0.f},{0.f,0.f},{0.f,0.f},{0.f,0.f}};
    if (g == 0)
        addrow(*(const uint4*)&h[(size_t)v * 128 + (li << 3)], dv, a4);
    int e = beg + g;
    for (; e + 12 < end; e += 16) {
        int s0 = col[e], s1 = col[e + 4], s2 = col[e + 8], s3 = col[e + 12];
        float d0 = dinv[s0], d1 = dinv[s1], d2 = dinv[s2], d3 = dinv[s3];
        uint4 u0 = *(const uint4*)&h[(size_t)s0 * 128 + (li << 3)];
        uint4 u1 = *(const uint4*)&h[(size_t)s1 * 128 + (li << 3)];
        uint4 u2 = *(const uint4*)&h[(size_t)s2 * 128 + (li << 3)];
        uint4 u3 = *(const uint4*)&h[(size_t)s3 * 128 + (li << 3)];
        addrow(u0, d0, a4); addrow(u1, d1, a4);
        addrow(u2, d2, a4); addrow(u3, d3, a4);
    }
    // predicated tail: <=3 remaining edges in this group, all loads issued together
    if (e < end) {
        int e1 = e + 4, e2 = e + 8;
        bool v1 = e1 < end, v2 = e2 < end;
        int s0 = col[e];
        int s1 = col[v1 ? e1 : e];
        int s2 = col[v2 ? e2 : e];
        float d0 = dinv[s0];
        float d1 = v1 ? dinv[s1] : 0.f;
        float d2 = v2 ? dinv[s2] : 0.f;
        uint4 u0 = *(const uint4*)&h[(size_t)s0 * 128 + (li << 3)];
        uint4 u1 = *(const uint4*)&h[(size_t)s1 * 128 + (li << 3)];
        uint4 u2 = *(const uint4*)&h[(size_t)s2 * 128 + (li << 3)];
        addrow(u0, d0, a4); addrow(u1, d1, a4); addrow(u2, d2, a4);
    }

    float a[8];
#pragma unroll
    for (int j = 0; j < 4; ++j) { a[2 * j] = a4[j][0]; a[2 * j + 1] = a4[j][1]; }
#pragma unroll
    for (int off = 16; off <= 32; off <<= 1)
#pragma unroll
        for (int j = 0; j < 8; ++j) a[j] += __shfl_xor(a[j], off);
    if (g == 0) {
        bf16x8 hh, ll;
#pragma unroll
        for (int j = 0; j < 8; ++j) {
            float o = fmaxf(fmaf(a[j], dv, bias[(li << 3) + j]), 0.f);
            short hb = f2bf(o);
            hh[j] = hb;
            ll[j] = f2bf(o - bf2f(hb));
        }
        short* dst = &xoI[((size_t)orow << 8) + (li << 4)];
        *(bf16x8*)dst = hh;
        *(bf16x8*)(dst + 8) = ll;
    }
}

__global__ __launch_bounds__(256) void k_agg(
    const short* __restrict__ h, const int* __restrict__ col,
    const int* __restrict__ offs, const int* __restrict__ ends,
    const float* __restrict__ dinv, const float* __restrict__ bias,
    short* __restrict__ xoI, int n) {
    int v = (blockIdx.x << 2) + (threadIdx.x >> 6);
    if (v >= n) return;
    agg_body(h, col, offs, ends, dinv, bias, xoI, v, v);
}

__global__ __launch_bounds__(256) void k_agg3(
    const short* __restrict__ h, const int* __restrict__ col,
    const int* __restrict__ offs, const int* __restrict__ ends,
    const float* __restrict__ dinv, const float* __restrict__ bias,
    short* __restrict__ xoI, const int* __restrict__ sidx,
    const int* __restrict__ tidx) {
    int i = (blockIdx.x << 2) + (threadIdx.x >> 6);
    if (i >= 2 * BATCH) return;
    int v = (i < BATCH) ? sidx[i] : tidx[i - BATCH];
    agg_body(h, col, offs, ends, dinv, bias, xoI, v, i);
}

// ---------------- fused P/Q projection + dot (unchanged) ----------------

__global__ __launch_bounds__(256) void k_pq(
    const short* __restrict__ a1I, const short* __restrict__ a2I,
    const short* __restrict__ x3I, const short* __restrict__ wI,
    const int* __restrict__ sidx, const int* __restrict__ tidx,
    const float* __restrict__ bp, const float* __restrict__ bw,
    float* __restrict__ out) {
    __shared__ float Ps[32][132];
    __shared__ float Qs[32][132];
    int t = threadIdx.x;
    int lane = t & 63, wave = t >> 6;
    int isQ = wave >> 1, wn = wave & 1;
    int l15 = lane & 15;
    int g16 = (lane >> 4) << 4;
    int pairBase = blockIdx.x << 5;
    int colBase = wn << 6;
    const int* gidx = isQ ? tidx : sidx;
    const float* bias = isQ ? bw : bp;
    int r0i = pairBase + l15;
    int r1i = r0i + 16;
    long long n0 = (long long)gidx[r0i];
    long long n1 = (long long)gidx[r1i];

    fx4 acc[2][4];
#pragma unroll
    for (int i = 0; i < 2; ++i)
#pragma unroll
        for (int j = 0; j < 4; ++j) {
            acc[i][j][0] = 0.f; acc[i][j][1] = 0.f;
            acc[i][j][2] = 0.f; acc[i][j][3] = 0.f;
        }

#pragma unroll
    for (int c = 0; c < 3; ++c) {
        const short* AI = (c == 0) ? a1I : (c == 1) ? a2I : x3I;
        long long b0 = (c == 2) ? (long long)(r0i + (isQ << 14)) : n0;
        long long b1 = (c == 2) ? (long long)(r1i + (isQ << 14)) : n1;
        const short* WB = wI + (size_t)(3 + isQ * 3 + c) * 32768;
#pragma unroll
        for (int ks = 0; ks < 4; ++ks) {
            int co = (ks << 6) + g16;
            const short* ap0 = &AI[(b0 << 8) + co];
            const short* ap1 = &AI[(b1 << 8) + co];
            bf16x8 a0h = *(const bf16x8*)ap0;
            bf16x8 a0l = *(const bf16x8*)(ap0 + 8);
            bf16x8 a1h = *(const bf16x8*)ap1;
            bf16x8 a1l = *(const bf16x8*)(ap1 + 8);
#pragma unroll
            for (int fc = 0; fc < 4; ++fc) {
                int cc = colBase + (fc << 4) + l15;
                const short* bpp = &WB[((size_t)cc << 8) + co];
                bf16x8 bh = *(const bf16x8*)bpp;
                bf16x8 bl = *(const bf16x8*)(bpp + 8);
                acc[0][fc] = __builtin_amdgcn_mfma_f32_16x16x32_bf16(a0h, bh, acc[0][fc], 0, 0, 0);
                acc[0][fc] = __builtin_amdgcn_mfma_f32_16x16x32_bf16(a0h, bl, acc[0][fc], 0, 0, 0);
                acc[0][fc] = __builtin_amdgcn_mfma_f32_16x16x32_bf16(a0l, bh, acc[0][fc], 0, 0, 0);
                acc[1][fc] = __builtin_amdgcn_mfma_f32_16x16x32_bf16(a1h, bh, acc[1][fc], 0, 0, 0);
                acc[1][fc] = __builtin_amdgcn_mfma_f32_16x16x32_bf16(a1h, bl, acc[1][fc], 0, 0, 0);
                acc[1][fc] = __builtin_amdgcn_mfma_f32_16x16x32_bf16(a1l, bh, acc[1][fc], 0, 0, 0);
            }
        }
    }

    int rq = (lane >> 4) << 2;
    float (*dst)[132] = isQ ? Qs : Ps;
#pragma unroll
    for (int fr = 0; fr < 2; ++fr) {
#pragma unroll
        for (int fc = 0; fc < 4; ++fc) {
            int cg = colBase + (fc << 4) + l15;
            float bv = bias[cg];
#pragma unroll
            for (int rg = 0; rg < 4; ++rg)
                dst[(fr << 4) + rq + rg][cg] = acc[fr][fc][rg] + bv;
        }
    }
    __syncthreads();

    int p = t >> 3, seg = t & 7;
    const float* pr = &Ps[p][seg * 16];
    const float* qr = &Qs[p][seg * 16];
    float s = 0.f;
#pragma unroll
    for (int j = 0; j < 16; ++j) s += pr[j] * qr[j];
    s += __shfl_xor(s, 1);
    s += __shfl_xor(s, 2);
    s += __shfl_xor(s, 4);
    if (seg == 0) out[pairBase + p] = s;
}

// ---------------- launch ----------------

extern "C" void kernel_launch(void* const* d_in, const int* in_sizes, int n_in,
                              void* d_out, int out_size, void* d_ws, size_t ws_size,
                              hipStream_t stream) {
    const float* x    = (const float*)d_in[0];
    const int*   edge = (const int*)d_in[1];
    const int*   sidx = (const int*)d_in[2];
    const int*   tidx = (const int*)d_in[3];
    const float* Wc0  = (const float*)d_in[4];
    const float* bc0  = (const float*)d_in[5];
    const float* Wc1  = (const float*)d_in[6];
    const float* bc1  = (const float*)d_in[7];
    const float* Wc2  = (const float*)d_in[8];
    const float* bc2  = (const float*)d_in[9];
    const float* Ww   = (const float*)d_in[10];
    const float* bw   = (const float*)d_in[11];
    const float* Wp   = (const float*)d_in[12];
    const float* bp   = (const float*)d_in[13];
    float* out = (float*)d_out;

    char* base = (char*)d_ws;
    size_t off = 0;
    auto alloc = [&](size_t bytes) -> char* {
        char* p = base + off;
        off = (off + bytes + 255) & ~(size_t)255;
        return p;
    };
    const size_t ISZ = (size_t)N_NODES * 256 * sizeof(short);
    const size_t XSZ = (size_t)2 * BATCH * 256 * sizeof(short);
    short* a1I  = (short*)alloc(ISZ);
    short* a2I  = (short*)alloc(ISZ);
    short* x3I  = (short*)alloc(XSZ);
    short* hbf  = (short*)alloc((size_t)N_NODES * HID * sizeof(short));
    int*   offsets = (int*)alloc((size_t)N_NODES * sizeof(int));
    int*   endsA   = (int*)alloc((size_t)N_NODES * sizeof(int));
    int*   colArr  = (int*)alloc((size_t)NB * CAP * sizeof(int));
    unsigned* tmp  = (unsigned*)alloc((size_t)NB * CAP * sizeof(unsigned));
    float* dinv    = (float*)alloc((size_t)N_NODES * sizeof(float));
    int*   bcur    = (int*)alloc(256 * sizeof(int));
    short* wI      = (short*)alloc((size_t)9 * 32768 * sizeof(short));
    (void)ws_size; (void)in_sizes; (void)n_in; (void)out_size;

    // ---- CSR build + weight prep (fused into passA grid) ----
    hipMemsetAsync(bcur, 0, NB * sizeof(int), stream);
    k_passA<<<PA_BLOCKS + 9, 256, 0, stream>>>(edge, bcur, tmp, N_EDGES,
                                               Wc0, Wc1, Wc2, Wp, Ww, wI);
    k_passB<<<NB, 256, 0, stream>>>(tmp, bcur, offsets, endsA, dinv, colArr);

    const int aggGrid  = (N_NODES + 3) / 4;
    const int agg3Grid = (2 * BATCH) / 4;
    const int gemmGrid = 512;
#define WI(c) (wI + (size_t)(c) * 32768)

    // ---- layer 1 ----
    k_sgemm<1><<<gemmGrid, 256, 0, stream>>>((const char*)x, WI(0), hbf, N_NODES);
    k_agg<<<aggGrid, 256, 0, stream>>>(hbf, colArr, offsets, endsA, dinv, bc0, a1I, N_NODES);

    // ---- layer 2 ----
    k_sgemm<0><<<gemmGrid, 256, 0, stream>>>((const char*)a1I, WI(1), hbf, N_NODES);
    k_agg<<<aggGrid, 256, 0, stream>>>(hbf, colArr, offsets, endsA, dinv, bc1, a2I, N_NODES);

    // ---- layer 3 (batch nodes only) ----
    k_sgemm<0><<<gemmGrid, 256, 0, stream>>>((const char*)a2I, WI(2), hbf, N_NODES);
    k_agg3<<<agg3Grid, 256, 0, stream>>>(hbf, colArr, offsets, endsA, dinv, bc2, x3I, sidx, tidx);

    // ---- fused P/Q + dot ----
    k_pq<<<BATCH / 32, 256, 0, stream>>>(a1I, a2I, x3I, wI, sidx, tidx, bp, bw, out);
}